// Round 7
// baseline (339.229 us; speedup 1.0000x reference)
//
#include <hip/hip_runtime.h>
#include <hip/hip_bf16.h>
#include <math.h>

#define N_NODES 50000
#define N_EDGES 400000
#define HEADS 6
#define DIMS 32
#define FEAT 192
#define NEG_SLOPE 0.2f

typedef __attribute__((ext_vector_type(8))) short short8;
typedef __attribute__((ext_vector_type(4))) float f32x4;

__device__ __forceinline__ unsigned short f2bu(float f) {
    __hip_bfloat16 h = __float2bfloat16(f);
    unsigned short u; __builtin_memcpy(&u, &h, 2); return u;
}
__device__ __forceinline__ float bu2f(unsigned short u) {
    return __uint_as_float(((unsigned)u) << 16);
}

// ---------------- workspace layout (byte offsets) ----------------
#define XL_OFF    0            // ushort N*192 = 19,200,000
#define XR_OFF    19200000     // ushort N*192
#define WT_OFF    38400000     // short 384*192 = 147,456
#define BLR_OFF   38547456     // float 384
#define PAIR_OFF  38548992     // int2 E = 3,200,000
#define DEG_OFF   41748992     // int N = 200,000
#define SCAN_OFF  42148992     // int N
#define BSUM_OFF  42348992     // int 256
#define BOFF_OFF  42350016     // int 256
#define NB_SCAN ((N_NODES + 255) / 256)   // 196

// ---------------- count (1 atomic/edge) + fused weight pack ----------------
__global__ __launch_bounds__(256) void k_count(const int* __restrict__ ei,
                                               int* __restrict__ deg,
                                               const float* __restrict__ Wl,
                                               const float* __restrict__ Wr,
                                               const float* __restrict__ bl,
                                               const float* __restrict__ br,
                                               short* __restrict__ Wt,
                                               float* __restrict__ blr) {
    int e = blockIdx.x * blockDim.x + threadIdx.x;
    if (e < N_EDGES) atomicAdd(&deg[ei[N_EDGES + e]], 1);
    if (e < 384 * FEAT) {   // pack Wt[n][k] = W[k][n] (bf16)
        int n = e / FEAT, k = e - n * FEAT;
        float v = (n < FEAT) ? Wl[k * FEAT + n] : Wr[k * FEAT + (n - FEAT)];
        Wt[n * FEAT + k] = (short)f2bu(v);
    }
    if (e < 384) blr[e] = (e < FEAT) ? bl[e] : br[e - FEAT];
}

__global__ __launch_bounds__(256) void k_scan1(const int* __restrict__ deg,
                                               int* __restrict__ scan,
                                               int* __restrict__ bsums) {
    int t = threadIdx.x;
    int i = blockIdx.x * 256 + t;
    int v = (i < N_NODES) ? deg[i] : 0;
    __shared__ int s[256];
    s[t] = v; __syncthreads();
    for (int off = 1; off < 256; off <<= 1) {
        int u = (t >= off) ? s[t - off] : 0;
        __syncthreads();
        s[t] += u;
        __syncthreads();
    }
    if (i < N_NODES) scan[i] = s[t];   // inclusive within block
    if (t == 255) bsums[blockIdx.x] = s[255];
}

__global__ __launch_bounds__(256) void k_scan2(int* __restrict__ bsums,
                                               int* __restrict__ boffs) {
    int t = threadIdx.x;
    int v = (t < NB_SCAN) ? bsums[t] : 0;
    __shared__ int s[256];
    s[t] = v; __syncthreads();
    for (int off = 1; off < 256; off <<= 1) {
        int u = (t >= off) ? s[t - off] : 0;
        __syncthreads();
        s[t] += u;
        __syncthreads();
    }
    boffs[t] = s[t] - v;   // exclusive block offsets
}

// ---------------- fused scatter + MFMA GEMM (block-range split) ----------------
#define SCAT_BLOCKS ((N_EDGES + 383) / 384)   // 1042
#define GEMM_BLOCKS (N_NODES / 16)            // 3125
#define OSTRIDE 392
#define ASTRIDE 200
__global__ __launch_bounds__(384) void k_scatgemm(const int* __restrict__ ei,
                                                  const float* __restrict__ ew,
                                                  const int* __restrict__ scan,
                                                  const int* __restrict__ boffs,
                                                  int* __restrict__ deg,
                                                  int2* __restrict__ pair,
                                                  const float* __restrict__ x,
                                                  const short* __restrict__ Wt,
                                                  const float* __restrict__ blr,
                                                  unsigned short* __restrict__ xl,
                                                  unsigned short* __restrict__ xr) {
    __shared__ unsigned short sOut[16 * OSTRIDE];
    __shared__ unsigned short sA[16 * ASTRIDE];
    if (blockIdx.x < SCAT_BLOCKS) {
        int e = blockIdx.x * 384 + threadIdx.x;
        if (e < N_EDGES) {
            int d = ei[N_EDGES + e];
            int inclEnd = boffs[d >> 8] + scan[d];
            int old = atomicSub(&deg[d], 1);     // old in [1, deg]
            int2 p; p.x = ei[e]; p.y = __float_as_int(ew[e]);
            pair[inclEnd - old] = p;
        }
        return;
    }
    size_t row0 = (size_t)(blockIdx.x - SCAT_BLOCKS) * 16;

    {
        int q = threadIdx.x;
        int row = q / 24, k0 = (q - row * 24) * 8;
        const float* ap = x + (row0 + row) * FEAT + k0;
        float4 v0 = *(const float4*)ap;
        float4 v1 = *(const float4*)(ap + 4);
        unsigned short tmp[8];
        tmp[0] = f2bu(v0.x); tmp[1] = f2bu(v0.y); tmp[2] = f2bu(v0.z); tmp[3] = f2bu(v0.w);
        tmp[4] = f2bu(v1.x); tmp[5] = f2bu(v1.y); tmp[6] = f2bu(v1.z); tmp[7] = f2bu(v1.w);
        int kw = (k0 >> 1) ^ ((row & 7) << 2);
        *(uint4*)&sA[row * ASTRIDE + kw * 2] = *(const uint4*)tmp;
    }
    __syncthreads();

    int wv   = threadIdx.x >> 6;
    int lane = threadIdx.x & 63;
    int m    = lane & 15;
    int kg   = lane >> 4;
    int ncol0 = wv * 64;

    f32x4 acc0 = {0.f,0.f,0.f,0.f}, acc1 = acc0, acc2 = acc0, acc3 = acc0;

#pragma unroll
    for (int ks = 0; ks < 6; ks++) {
        int kb = ks * 32 + kg * 8;
        int kw = (kb >> 1) ^ ((m & 7) << 2);
        short8 af = *(const short8*)&sA[m * ASTRIDE + kw * 2];
        const short* wp = Wt + (size_t)(ncol0 + m) * FEAT + kb;
        short8 b0 = *(const short8*)(wp);
        short8 b1 = *(const short8*)(wp + 16 * FEAT);
        short8 b2 = *(const short8*)(wp + 32 * FEAT);
        short8 b3 = *(const short8*)(wp + 48 * FEAT);
        acc0 = __builtin_amdgcn_mfma_f32_16x16x32_bf16(af, b0, acc0, 0, 0, 0);
        acc1 = __builtin_amdgcn_mfma_f32_16x16x32_bf16(af, b1, acc1, 0, 0, 0);
        acc2 = __builtin_amdgcn_mfma_f32_16x16x32_bf16(af, b2, acc2, 0, 0, 0);
        acc3 = __builtin_amdgcn_mfma_f32_16x16x32_bf16(af, b3, acc3, 0, 0, 0);
    }

    f32x4 accs[4] = {acc0, acc1, acc2, acc3};
#pragma unroll
    for (int t4 = 0; t4 < 4; t4++) {
        int cc = ncol0 + t4 * 16 + m;
        float bv = blr[cc];
#pragma unroll
        for (int r = 0; r < 4; r++) {
            sOut[(kg * 4 + r) * OSTRIDE + cc] = f2bu(accs[t4][r] + bv);
        }
    }
    __syncthreads();
    for (int q = threadIdx.x; q < 768; q += 384) {
        int row = q / 48, p = q - row * 48;
        uint4 v = *(const uint4*)&sOut[row * OSTRIDE + p * 8];
        if (p < 24) *(uint4*)(xl + (row0 + row) * FEAT + p * 8) = v;
        else        *(uint4*)(xr + (row0 + row) * FEAT + (p - 24) * 8) = v;
    }
}

// ---------------- fused node kernel: coarse-grain (r3 phase code, 2x grain) ----
// 16 nodes/block, 384 threads (6 waves), 64-edge chunks. Per 64 edges: ONE
// gather-wait + 3 barriers (was two waits + 6); prologue/epilogue amortized 2x.
// LDS ~37.7KB -> 4 blocks/CU x 6 waves = 24 waves/CU static (same as r3/r6).
// E-phase: two 192-thread groups, each owns 8 nodes (acc[8], VGPR ~64).
// den on 96 threads; wsm on 16 spare threads (no k_count atomics).
#define NPB 16
#define CEDGE 64
#define RS 100   // uints per row; rows 16B aligned; 100 % 32 = 4 spreads banks
#define APAD 36  // att/We row stride (float4-aligned)
__global__ __launch_bounds__(384) void k_node(const float* __restrict__ x,
                                              const float* __restrict__ bias,
                                              const float* __restrict__ att,
                                              const float* __restrict__ We,
                                              const int* __restrict__ scan,
                                              const int* __restrict__ boffs,
                                              const int2* __restrict__ pair,
                                              const unsigned short* __restrict__ xl,
                                              const unsigned short* __restrict__ xr,
                                              float* __restrict__ out) {
    __shared__ __align__(16) unsigned int sXL[CEDGE * RS];
    __shared__ __align__(16) unsigned int sXR[NPB * RS];
    __shared__ float sEx[CEDGE * HEADS];
    __shared__ float sExS[NPB * HEADS];
    __shared__ int   sSrc[2][CEDGE];
    __shared__ float sW[2][CEDGE];
    __shared__ int   sDst[2][CEDGE];
    __shared__ int   sStart[NPB + 1];
    __shared__ __align__(16) float sAttP[HEADS * APAD];
    __shared__ __align__(16) float sWeP[HEADS * APAD];
    __shared__ float sDen[NPB * HEADS];
    __shared__ float sWsm[NPB];

    int t = threadIdx.x;
    int n0 = blockIdx.x * NPB;

    // per-thread gbase/etot (uniform -> scalar loads); enables pre-sync pair load
    int gbase = boffs[n0 >> 8] + ((n0 & 255) ? scan[n0 - 1] : 0);
    int n16 = n0 + NPB;
    int gend = (n16 >= N_NODES) ? N_EDGES
             : (boffs[n16 >> 8] + ((n16 & 255) ? scan[n16 - 1] : 0));
    int etot = gend - gbase;
    int c0 = min(etot, CEDGE);

    // chunk-0 pair -> sSrc[0]/sW[0] (pre-sync)
    if (t < c0) { int2 p = pair[gbase + t]; sSrc[0][t] = p.x; sW[0][t] = __int_as_float(p.y); }

    for (int q = t; q < HEADS * APAD; q += 384) {
        int hh = q / APAD, c = q - hh * APAD;
        if (c < 32) { sAttP[q] = att[hh * 32 + c]; sWeP[q] = We[hh * 32 + c]; }
    }
    if (t <= NPB) {
        int n = n0 + t;
        int st;
        if (n >= N_NODES) st = N_EDGES;
        else {
            int b = n >> 8;
            st = boffs[b] + ((n & 255) ? scan[n - 1] : 0);
        }
        sStart[t] = st;
    }
    if (t < NPB) {   // sDst[0] pre-fill with self-computed bounds (no sStart dep)
        int n = n0 + t;
        int a = boffs[n >> 8] + ((n & 255) ? scan[n - 1] : 0);
        int n1 = n + 1;
        int b = (n1 >= N_NODES) ? N_EDGES
              : (boffs[n1 >> 8] + ((n1 & 255) ? scan[n1 - 1] : 0));
        int lo = a - gbase; if (lo < 0) lo = 0;
        int hi = b - gbase; if (hi > c0) hi = c0;
        for (int q = lo; q < hi; q++) sDst[0][q] = t;
    }
    {   // stage this block's 16 xr rows: 384 = 16 rows x 24 uint4
        int nn = t / 24, p = t - nn * 24;
        *(uint4*)&sXR[nn * RS + p * 4] = ((const uint4*)(xr + (size_t)(n0 + nn) * FEAT))[p];
    }
    __syncthreads();

    float acc[8];
#pragma unroll
    for (int nn = 0; nn < 8; nn++) acc[nn] = 0.f;
    float denR = 0.f, wsP = 0.f;
    int grp  = t / 192;              // node-group: 0 -> nodes 0..7, 1 -> 8..15
    int ch   = t - grp * 192;        // channel 0..191 within group
    int h    = ch >> 5;              // head for channel role
    int cw   = ch >> 1;              // word index within row
    int base = grp * 8;              // first local node of this group
    int nnD = t / HEADS, hhD = t - nnD * HEADS;   // den ownership (t < 96)

    int nch = (etot + CEDGE - 1) / CEDGE;
    for (int ci = 0; ci < nch; ci++) {
        int i0 = ci * CEDGE;
        int c  = min(etot - i0, CEDGE);
        int cn = min(etot - i0 - CEDGE, CEDGE);   // next chunk size
        int cb = ci & 1, nb = cb ^ 1;

        // A: gather xl chunk ci -> sXL (up to 1536 uint4, 4/thread);
        //    overlap: prefetch pair ci+1 -> regs; fill sDst[nb]
        {
            int nld = c * 24;
#pragma unroll
            for (int s = 0; s < 4; s++) {
                int q = t + s * 384;
                if (q < nld) {
                    int i = q / 24, p = q - i * 24;
                    *(uint4*)&sXL[i * RS + p * 4] =
                        *(const uint4*)(xl + (size_t)sSrc[cb][i] * FEAT + p * 8);
                }
            }
        }
        int2 P;
        if (t < cn) P = pair[gbase + i0 + CEDGE + t];
        if (t < NPB && cn > 0) {
            int lo = sStart[t] - gbase - i0 - CEDGE;     if (lo < 0) lo = 0;
            int hi = sStart[t + 1] - gbase - i0 - CEDGE; if (hi > cn) hi = cn;
            for (int q = lo; q < hi; q++) sDst[nb][q] = t;
        }
        __syncthreads();

        // C: alpha + exp for chunk ci (thread = (edge, head), up to 64*6=384);
        //    commit pair regs -> sSrc/sW[nb]
        if (t < c * HEADS) {
            int i = t / HEADS, hh = t - i * HEADS;
            int nn = sDst[cb][i];
            float w = sW[cb][i];
            const uint4* pa = (const uint4*)&sXL[i * RS + hh * 16];
            const uint4* pb = (const uint4*)&sXR[nn * RS + hh * 16];
            float alpha = 0.f;
#pragma unroll
            for (int g = 0; g < 4; g++) {
                uint4 a4 = pa[g];
                uint4 b4 = pb[g];
                float4 we0 = *(const float4*)&sWeP[hh * APAD + g * 8];
                float4 we1 = *(const float4*)&sWeP[hh * APAD + g * 8 + 4];
                float4 at0 = *(const float4*)&sAttP[hh * APAD + g * 8];
                float4 at1 = *(const float4*)&sAttP[hh * APAD + g * 8 + 4];
                float wec[8] = {we0.x, we0.y, we0.z, we0.w, we1.x, we1.y, we1.z, we1.w};
                float atc[8] = {at0.x, at0.y, at0.z, at0.w, at1.x, at1.y, at1.z, at1.w};
                unsigned aw[4] = {a4.x, a4.y, a4.z, a4.w};
                unsigned bw[4] = {b4.x, b4.y, b4.z, b4.w};
#pragma unroll
                for (int q = 0; q < 4; q++) {
                    float m0 = bu2f((unsigned short)aw[q]) + bu2f((unsigned short)bw[q]) + w * wec[q * 2];
                    m0 = fmaxf(m0, NEG_SLOPE * m0);
                    alpha += m0 * atc[q * 2];
                    float m1 = bu2f((unsigned short)(aw[q] >> 16)) + bu2f((unsigned short)(bw[q] >> 16)) + w * wec[q * 2 + 1];
                    m1 = fmaxf(m1, NEG_SLOPE * m1);
                    alpha += m1 * atc[q * 2 + 1];
                }
            }
            sEx[t] = __expf(alpha);
        }
        if (t < cn) { sSrc[nb][t] = P.x; sW[nb][t] = __int_as_float(P.y); }
        __syncthreads();

        // E: accumulate (each 192-group covers its 8 nodes) + den(96) + wsm(16)
        {
#pragma unroll
            for (int nn = 0; nn < 8; nn++) {
                int lo = sStart[base + nn] - gbase - i0;     if (lo < 0) lo = 0;
                int hi = sStart[base + nn + 1] - gbase - i0; if (hi > c) hi = c;
                for (int i = lo; i < hi; i++) {
                    float ex = sEx[i * HEADS + h];
                    unsigned u = sXL[i * RS + cw];
                    unsigned short v = (ch & 1) ? (unsigned short)(u >> 16) : (unsigned short)u;
                    acc[nn] += ex * bu2f(v);
                }
            }
            if (t < NPB * HEADS) {
                int lo = sStart[nnD] - gbase - i0;     if (lo < 0) lo = 0;
                int hi = sStart[nnD + 1] - gbase - i0; if (hi > c) hi = c;
                for (int i = lo; i < hi; i++) denR += sEx[i * HEADS + hhD];
            } else if (t < NPB * HEADS + NPB) {
                int nw = t - NPB * HEADS;
                int lo = sStart[nw] - gbase - i0;     if (lo < 0) lo = 0;
                int hi = sStart[nw + 1] - gbase - i0; if (hi > c) hi = c;
                for (int i = lo; i < hi; i++) wsP += sW[cb][i];
            }
        }
        __syncthreads();   // protects sXL/sDst overwrite next iter
    }

    if (t < NPB * HEADS) sDen[t] = denR;
    else if (t < NPB * HEADS + NPB) sWsm[t - NPB * HEADS] = wsP;
    __syncthreads();

    // self-loop alpha (w = mean incoming weight); self xl row read from GLOBAL
    if (t < NPB * HEADS) {
        int nn = nnD, hh = hhD;
        int dg = sStart[nn + 1] - sStart[nn];
        float w = sWsm[nn] / fmaxf((float)dg, 1.0f);
        const uint4* pa = (const uint4*)(xl + (size_t)(n0 + nn) * FEAT + hh * 32);
        const uint4* pb = (const uint4*)&sXR[nn * RS + hh * 16];
        float alpha = 0.f;
#pragma unroll
        for (int g = 0; g < 4; g++) {
            uint4 a4 = pa[g];
            uint4 b4 = pb[g];
            float4 we0 = *(const float4*)&sWeP[hh * APAD + g * 8];
            float4 we1 = *(const float4*)&sWeP[hh * APAD + g * 8 + 4];
            float4 at0 = *(const float4*)&sAttP[hh * APAD + g * 8];
            float4 at1 = *(const float4*)&sAttP[hh * APAD + g * 8 + 4];
            float wec[8] = {we0.x, we0.y, we0.z, we0.w, we1.x, we1.y, we1.z, we1.w};
            float atc[8] = {at0.x, at0.y, at0.z, at0.w, at1.x, at1.y, at1.z, at1.w};
            unsigned aw[4] = {a4.x, a4.y, a4.z, a4.w};
            unsigned bw[4] = {b4.x, b4.y, b4.z, b4.w};
#pragma unroll
            for (int q = 0; q < 4; q++) {
                float m0 = bu2f((unsigned short)aw[q]) + bu2f((unsigned short)bw[q]) + w * wec[q * 2];
                m0 = fmaxf(m0, NEG_SLOPE * m0);
                alpha += m0 * atc[q * 2];
                float m1 = bu2f((unsigned short)(aw[q] >> 16)) + bu2f((unsigned short)(bw[q] >> 16)) + w * wec[q * 2 + 1];
                m1 = fmaxf(m1, NEG_SLOPE * m1);
                alpha += m1 * atc[q * 2 + 1];
            }
        }
        sExS[t] = __expf(alpha);
    }
    __syncthreads();

    // epilogue: self-loop add, divide, residual + bias + relu (self xl from global)
    {
        float bj = bias[ch];
#pragma unroll
        for (int nn = 0; nn < 8; nn++) {
            int ln = base + nn;
            float exS = sExS[ln * HEADS + h];
            size_t off = (size_t)(n0 + ln) * FEAT + ch;
            float xsv = bu2f(xl[off]);
            float num = acc[nn] + exS * xsv;
            float dn  = sDen[ln * HEADS + h] + exS;
            float val = x[off] + bj + num / dn;
            out[off] = (val > 0.f) ? val : 0.f;
        }
    }
}

extern "C" void kernel_launch(void* const* d_in, const int* in_sizes, int n_in,
                              void* d_out, int out_size, void* d_ws, size_t ws_size,
                              hipStream_t stream) {
    const float* x    = (const float*)d_in[0];
    const int*   ei   = (const int*)d_in[1];
    const float* ew   = (const float*)d_in[2];
    const float* Wl   = (const float*)d_in[3];
    const float* bl   = (const float*)d_in[4];
    const float* Wr   = (const float*)d_in[5];
    const float* br   = (const float*)d_in[6];
    const float* We   = (const float*)d_in[7];
    const float* att  = (const float*)d_in[8];
    const float* bias = (const float*)d_in[9];
    float* out = (float*)d_out;

    char* ws = (char*)d_ws;
    unsigned short* xl = (unsigned short*)(ws + XL_OFF);
    unsigned short* xr = (unsigned short*)(ws + XR_OFF);
    short* Wt     = (short*)(ws + WT_OFF);
    float* blr    = (float*)(ws + BLR_OFF);
    int2*  pair   = (int2*)(ws + PAIR_OFF);
    int*   deg    = (int*)(ws + DEG_OFF);
    int*   scan   = (int*)(ws + SCAN_OFF);
    int*   bsums  = (int*)(ws + BSUM_OFF);
    int*   boffs  = (int*)(ws + BOFF_OFF);

    // zero deg; harness poisons ws with 0xAA
    hipMemsetAsync(ws + DEG_OFF, 0, N_NODES * sizeof(int), stream);

    k_count<<<(N_EDGES + 255) / 256, 256, 0, stream>>>(ei, deg, Wl, Wr, bl, br, Wt, blr);
    k_scan1<<<NB_SCAN, 256, 0, stream>>>(deg, scan, bsums);
    k_scan2<<<1, 256, 0, stream>>>(bsums, boffs);

    k_scatgemm<<<SCAT_BLOCKS + GEMM_BLOCKS, 384, 0, stream>>>(ei, ew, scan, boffs, deg,
                                                              pair, x, Wt, blr, xl, xr);

    k_node<<<N_NODES / NPB, 384, 0, stream>>>(x, bias, att, We, scan, boffs,
                                              pair, xl, xr, out);
}

// Round 8
// 284.685 us; speedup vs baseline: 1.1916x; 1.1916x over previous
//
#include <hip/hip_runtime.h>
#include <hip/hip_bf16.h>
#include <math.h>

#define N_NODES 50000
#define N_EDGES 400000
#define HEADS 6
#define DIMS 32
#define FEAT 192
#define NEG_SLOPE 0.2f

typedef __attribute__((ext_vector_type(8))) short short8;
typedef __attribute__((ext_vector_type(4))) float f32x4;

__device__ __forceinline__ unsigned short f2bu(float f) {
    __hip_bfloat16 h = __float2bfloat16(f);
    unsigned short u; __builtin_memcpy(&u, &h, 2); return u;
}
__device__ __forceinline__ float bu2f(unsigned short u) {
    return __uint_as_float(((unsigned)u) << 16);
}

// ---------------- workspace layout (byte offsets) ----------------
#define XL_OFF    0            // ushort N*192 = 19,200,000
#define XR_OFF    19200000     // ushort N*192
#define WT_OFF    38400000     // short 384*192 = 147,456
#define BLR_OFF   38547456     // float 384
#define PAIR_OFF  38548992     // int2 E = 3,200,000
#define DEG_OFF   41748992     // int N = 200,000
#define SCAN_OFF  42148992     // int N
#define BSUM_OFF  42348992     // int 256
#define BOFF_OFF  42350016     // int 256
#define NB_SCAN ((N_NODES + 255) / 256)   // 196

// ---------------- count (1 atomic/edge) + fused weight pack ----------------
__global__ __launch_bounds__(256) void k_count(const int* __restrict__ ei,
                                               int* __restrict__ deg,
                                               const float* __restrict__ Wl,
                                               const float* __restrict__ Wr,
                                               const float* __restrict__ bl,
                                               const float* __restrict__ br,
                                               short* __restrict__ Wt,
                                               float* __restrict__ blr) {
    int e = blockIdx.x * blockDim.x + threadIdx.x;
    if (e < N_EDGES) atomicAdd(&deg[ei[N_EDGES + e]], 1);
    if (e < 384 * FEAT) {   // pack Wt[n][k] = W[k][n] (bf16)
        int n = e / FEAT, k = e - n * FEAT;
        float v = (n < FEAT) ? Wl[k * FEAT + n] : Wr[k * FEAT + (n - FEAT)];
        Wt[n * FEAT + k] = (short)f2bu(v);
    }
    if (e < 384) blr[e] = (e < FEAT) ? bl[e] : br[e - FEAT];
}

__global__ __launch_bounds__(256) void k_scan1(const int* __restrict__ deg,
                                               int* __restrict__ scan,
                                               int* __restrict__ bsums) {
    int t = threadIdx.x;
    int i = blockIdx.x * 256 + t;
    int v = (i < N_NODES) ? deg[i] : 0;
    __shared__ int s[256];
    s[t] = v; __syncthreads();
    for (int off = 1; off < 256; off <<= 1) {
        int u = (t >= off) ? s[t - off] : 0;
        __syncthreads();
        s[t] += u;
        __syncthreads();
    }
    if (i < N_NODES) scan[i] = s[t];   // inclusive within block
    if (t == 255) bsums[blockIdx.x] = s[255];
}

__global__ __launch_bounds__(256) void k_scan2(int* __restrict__ bsums,
                                               int* __restrict__ boffs) {
    int t = threadIdx.x;
    int v = (t < NB_SCAN) ? bsums[t] : 0;
    __shared__ int s[256];
    s[t] = v; __syncthreads();
    for (int off = 1; off < 256; off <<= 1) {
        int u = (t >= off) ? s[t - off] : 0;
        __syncthreads();
        s[t] += u;
        __syncthreads();
    }
    boffs[t] = s[t] - v;   // exclusive block offsets
}

// ---------------- fused scatter + MFMA GEMM (block-range split) ----------------
#define SCAT_BLOCKS ((N_EDGES + 383) / 384)   // 1042
#define GEMM_BLOCKS (N_NODES / 16)            // 3125
#define OSTRIDE 392
#define ASTRIDE 200
__global__ __launch_bounds__(384) void k_scatgemm(const int* __restrict__ ei,
                                                  const float* __restrict__ ew,
                                                  const int* __restrict__ scan,
                                                  const int* __restrict__ boffs,
                                                  int* __restrict__ deg,
                                                  int2* __restrict__ pair,
                                                  const float* __restrict__ x,
                                                  const short* __restrict__ Wt,
                                                  const float* __restrict__ blr,
                                                  unsigned short* __restrict__ xl,
                                                  unsigned short* __restrict__ xr) {
    __shared__ unsigned short sOut[16 * OSTRIDE];
    __shared__ unsigned short sA[16 * ASTRIDE];
    if (blockIdx.x < SCAT_BLOCKS) {
        int e = blockIdx.x * 384 + threadIdx.x;
        if (e < N_EDGES) {
            int d = ei[N_EDGES + e];
            int inclEnd = boffs[d >> 8] + scan[d];
            int old = atomicSub(&deg[d], 1);     // old in [1, deg]
            int2 p; p.x = ei[e]; p.y = __float_as_int(ew[e]);
            pair[inclEnd - old] = p;
        }
        return;
    }
    size_t row0 = (size_t)(blockIdx.x - SCAT_BLOCKS) * 16;

    {
        int q = threadIdx.x;
        int row = q / 24, k0 = (q - row * 24) * 8;
        const float* ap = x + (row0 + row) * FEAT + k0;
        float4 v0 = *(const float4*)ap;
        float4 v1 = *(const float4*)(ap + 4);
        unsigned short tmp[8];
        tmp[0] = f2bu(v0.x); tmp[1] = f2bu(v0.y); tmp[2] = f2bu(v0.z); tmp[3] = f2bu(v0.w);
        tmp[4] = f2bu(v1.x); tmp[5] = f2bu(v1.y); tmp[6] = f2bu(v1.z); tmp[7] = f2bu(v1.w);
        int kw = (k0 >> 1) ^ ((row & 7) << 2);
        *(uint4*)&sA[row * ASTRIDE + kw * 2] = *(const uint4*)tmp;
    }
    __syncthreads();

    int wv   = threadIdx.x >> 6;
    int lane = threadIdx.x & 63;
    int m    = lane & 15;
    int kg   = lane >> 4;
    int ncol0 = wv * 64;

    f32x4 acc0 = {0.f,0.f,0.f,0.f}, acc1 = acc0, acc2 = acc0, acc3 = acc0;

#pragma unroll
    for (int ks = 0; ks < 6; ks++) {
        int kb = ks * 32 + kg * 8;
        int kw = (kb >> 1) ^ ((m & 7) << 2);
        short8 af = *(const short8*)&sA[m * ASTRIDE + kw * 2];
        const short* wp = Wt + (size_t)(ncol0 + m) * FEAT + kb;
        short8 b0 = *(const short8*)(wp);
        short8 b1 = *(const short8*)(wp + 16 * FEAT);
        short8 b2 = *(const short8*)(wp + 32 * FEAT);
        short8 b3 = *(const short8*)(wp + 48 * FEAT);
        acc0 = __builtin_amdgcn_mfma_f32_16x16x32_bf16(af, b0, acc0, 0, 0, 0);
        acc1 = __builtin_amdgcn_mfma_f32_16x16x32_bf16(af, b1, acc1, 0, 0, 0);
        acc2 = __builtin_amdgcn_mfma_f32_16x16x32_bf16(af, b2, acc2, 0, 0, 0);
        acc3 = __builtin_amdgcn_mfma_f32_16x16x32_bf16(af, b3, acc3, 0, 0, 0);
    }

    f32x4 accs[4] = {acc0, acc1, acc2, acc3};
#pragma unroll
    for (int t4 = 0; t4 < 4; t4++) {
        int cc = ncol0 + t4 * 16 + m;
        float bv = blr[cc];
#pragma unroll
        for (int r = 0; r < 4; r++) {
            sOut[(kg * 4 + r) * OSTRIDE + cc] = f2bu(accs[t4][r] + bv);
        }
    }
    __syncthreads();
    for (int q = threadIdx.x; q < 768; q += 384) {
        int row = q / 48, p = q - row * 48;
        uint4 v = *(const uint4*)&sOut[row * OSTRIDE + p * 8];
        if (p < 24) *(uint4*)(xl + (row0 + row) * FEAT + p * 8) = v;
        else        *(uint4*)(xr + (row0 + row) * FEAT + (p - 24) * 8) = v;
    }
}

// ---------------- fused node kernel (r3 chassis + ILP) ----------------
// 8 nodes/block, 192 threads, 32-edge chunks (r3 = best measured chassis).
// New vs r3: E/den loops unrolled x2 (paired LDS loads halve exposed ds_read
// latency); dual alpha accumulators (halve dependent-FMA chain); wsm computed
// in-kernel on threads 48..55 (k_count stays atomic-light, r6's +22us win).
#define NPB 8
#define CEDGE 32
#define RS 100   // uints per row; rows 16B aligned; 100 % 32 = 4 spreads banks
#define APAD 36  // att/We row stride (float4-aligned)
__global__ __launch_bounds__(192) void k_node(const float* __restrict__ x,
                                              const float* __restrict__ bias,
                                              const float* __restrict__ att,
                                              const float* __restrict__ We,
                                              const int* __restrict__ scan,
                                              const int* __restrict__ boffs,
                                              const int2* __restrict__ pair,
                                              const unsigned short* __restrict__ xl,
                                              const unsigned short* __restrict__ xr,
                                              float* __restrict__ out) {
    __shared__ __align__(16) unsigned int sXL[CEDGE * RS];
    __shared__ __align__(16) unsigned int sXR[NPB * RS];
    __shared__ float sEx[CEDGE * HEADS];
    __shared__ float sExS[NPB * HEADS];
    __shared__ int   sSrc[2][CEDGE];
    __shared__ float sW[2][CEDGE];
    __shared__ int   sDst[2][CEDGE];
    __shared__ int   sStart[NPB + 1];
    __shared__ __align__(16) float sAttP[HEADS * APAD];
    __shared__ __align__(16) float sWeP[HEADS * APAD];
    __shared__ float sDen[NPB * HEADS];
    __shared__ float sWsm[NPB];

    int t = threadIdx.x;
    int h = t >> 5;                  // head for channel role
    int n0 = blockIdx.x * NPB;

    // per-thread gbase/etot (uniform -> scalar loads); enables pre-sync pair load
    int gbase = boffs[n0 >> 8] + ((n0 & 255) ? scan[n0 - 1] : 0);
    int n8 = n0 + NPB;
    int gend = (n8 >= N_NODES) ? N_EDGES
             : (boffs[n8 >> 8] + ((n8 & 255) ? scan[n8 - 1] : 0));
    int etot = gend - gbase;
    int c0 = min(etot, CEDGE);

    // chunk-0 pair -> sSrc[0]/sW[0] (pre-sync)
    if (t < c0) { int2 p = pair[gbase + t]; sSrc[0][t] = p.x; sW[0][t] = __int_as_float(p.y); }

    for (int q = t; q < HEADS * APAD; q += 192) {
        int hh = q / APAD, c = q - hh * APAD;
        if (c < 32) { sAttP[q] = att[hh * 32 + c]; sWeP[q] = We[hh * 32 + c]; }
    }
    if (t <= NPB) {
        int n = n0 + t;
        int st;
        if (n >= N_NODES) st = N_EDGES;
        else {
            int b = n >> 8;
            st = boffs[b] + ((n & 255) ? scan[n - 1] : 0);
        }
        sStart[t] = st;
    }
    if (t < NPB) {   // sDst[0] pre-fill with self-computed bounds (no sStart dep)
        int n = n0 + t;
        int a = boffs[n >> 8] + ((n & 255) ? scan[n - 1] : 0);
        int n1 = n + 1;
        int b = (n1 >= N_NODES) ? N_EDGES
              : (boffs[n1 >> 8] + ((n1 & 255) ? scan[n1 - 1] : 0));
        int lo = a - gbase; if (lo < 0) lo = 0;
        int hi = b - gbase; if (hi > c0) hi = c0;
        for (int q = lo; q < hi; q++) sDst[0][q] = t;
    }
    {   // stage this block's 8 xr rows: 192 = 8 rows x 24 uint4
        int nn = t / 24, p = t - nn * 24;
        *(uint4*)&sXR[nn * RS + p * 4] = ((const uint4*)(xr + (size_t)(n0 + nn) * FEAT))[p];
    }
    __syncthreads();

    float acc[NPB];
#pragma unroll
    for (int nn = 0; nn < NPB; nn++) acc[nn] = 0.f;
    float redR = 0.f;                               // den (t<48) OR wsm (t in [48,56))
    int nnD = t / HEADS, hhD = t - nnD * HEADS;     // den ownership (t < 48)

    int nch = (etot + CEDGE - 1) / CEDGE;
    for (int ci = 0; ci < nch; ci++) {
        int i0 = ci * CEDGE;
        int c  = min(etot - i0, CEDGE);
        int cn = min(etot - i0 - CEDGE, CEDGE);   // next chunk size
        int cb = ci & 1, nb = cb ^ 1;

        // A: gather xl chunk ci -> sXL; overlap: prefetch pair ci+1 -> regs; fill sDst[nb]
        {
            int nld = c * 24;
#pragma unroll
            for (int s = 0; s < 4; s++) {
                int q = t + s * 192;
                if (q < nld) {
                    int i = q / 24, p = q - i * 24;
                    *(uint4*)&sXL[i * RS + p * 4] =
                        *(const uint4*)(xl + (size_t)sSrc[cb][i] * FEAT + p * 8);
                }
            }
        }
        int2 P;
        if (t < cn) P = pair[gbase + i0 + CEDGE + t];
        if (t < NPB && cn > 0) {
            int lo = sStart[t] - gbase - i0 - CEDGE;     if (lo < 0) lo = 0;
            int hi = sStart[t + 1] - gbase - i0 - CEDGE; if (hi > cn) hi = cn;
            for (int q = lo; q < hi; q++) sDst[nb][q] = t;
        }
        __syncthreads();

        // C: alpha + exp for chunk ci (dual accumulators); commit pair regs -> nb
        if (t < c * HEADS) {
            int i = t / HEADS, hh = t - i * HEADS;
            int nn = sDst[cb][i];
            float w = sW[cb][i];
            const uint4* pa = (const uint4*)&sXL[i * RS + hh * 16];
            const uint4* pb = (const uint4*)&sXR[nn * RS + hh * 16];
            float alpha0 = 0.f, alpha1 = 0.f;
#pragma unroll
            for (int g = 0; g < 4; g++) {
                uint4 a4 = pa[g];
                uint4 b4 = pb[g];
                float4 we0 = *(const float4*)&sWeP[hh * APAD + g * 8];
                float4 we1 = *(const float4*)&sWeP[hh * APAD + g * 8 + 4];
                float4 at0 = *(const float4*)&sAttP[hh * APAD + g * 8];
                float4 at1 = *(const float4*)&sAttP[hh * APAD + g * 8 + 4];
                float wec[8] = {we0.x, we0.y, we0.z, we0.w, we1.x, we1.y, we1.z, we1.w};
                float atc[8] = {at0.x, at0.y, at0.z, at0.w, at1.x, at1.y, at1.z, at1.w};
                unsigned aw[4] = {a4.x, a4.y, a4.z, a4.w};
                unsigned bw[4] = {b4.x, b4.y, b4.z, b4.w};
#pragma unroll
                for (int q = 0; q < 4; q++) {
                    float m0 = bu2f((unsigned short)aw[q]) + bu2f((unsigned short)bw[q]) + w * wec[q * 2];
                    m0 = fmaxf(m0, NEG_SLOPE * m0);
                    alpha0 += m0 * atc[q * 2];
                    float m1 = bu2f((unsigned short)(aw[q] >> 16)) + bu2f((unsigned short)(bw[q] >> 16)) + w * wec[q * 2 + 1];
                    m1 = fmaxf(m1, NEG_SLOPE * m1);
                    alpha1 += m1 * atc[q * 2 + 1];
                }
            }
            sEx[t] = __expf(alpha0 + alpha1);
        }
        if (t < cn) { sSrc[nb][t] = P.x; sW[nb][t] = __int_as_float(P.y); }
        __syncthreads();

        // E: accumulate (x2 unroll, paired LDS loads) + den(48 thr) / wsm(8 thr)
        {
            int cw = t >> 1;
#pragma unroll
            for (int nn = 0; nn < NPB; nn++) {
                int lo = sStart[nn] - gbase - i0;     if (lo < 0) lo = 0;
                int hi = sStart[nn + 1] - gbase - i0; if (hi > c) hi = c;
                int i = lo;
                for (; i + 1 < hi; i += 2) {
                    float ex0 = sEx[i * HEADS + h];
                    float ex1 = sEx[(i + 1) * HEADS + h];
                    unsigned u0 = sXL[i * RS + cw];
                    unsigned u1 = sXL[(i + 1) * RS + cw];
                    unsigned short v0 = (t & 1) ? (unsigned short)(u0 >> 16) : (unsigned short)u0;
                    unsigned short v1 = (t & 1) ? (unsigned short)(u1 >> 16) : (unsigned short)u1;
                    acc[nn] += ex0 * bu2f(v0) + ex1 * bu2f(v1);
                }
                if (i < hi) {
                    float ex = sEx[i * HEADS + h];
                    unsigned u = sXL[i * RS + cw];
                    unsigned short v = (t & 1) ? (unsigned short)(u >> 16) : (unsigned short)u;
                    acc[nn] += ex * bu2f(v);
                }
            }
            if (t < NPB * HEADS) {
                int lo = sStart[nnD] - gbase - i0;     if (lo < 0) lo = 0;
                int hi = sStart[nnD + 1] - gbase - i0; if (hi > c) hi = c;
                int i = lo;
                for (; i + 1 < hi; i += 2)
                    redR += sEx[i * HEADS + hhD] + sEx[(i + 1) * HEADS + hhD];
                if (i < hi) redR += sEx[i * HEADS + hhD];
            } else if (t < NPB * HEADS + NPB) {
                int nw = t - NPB * HEADS;
                int lo = sStart[nw] - gbase - i0;     if (lo < 0) lo = 0;
                int hi = sStart[nw + 1] - gbase - i0; if (hi > c) hi = c;
                for (int i = lo; i < hi; i++) redR += sW[cb][i];
            }
        }
        __syncthreads();   // protects sXL/sDst overwrite next iter
    }

    if (t < NPB * HEADS) sDen[t] = redR;
    else if (t < NPB * HEADS + NPB) sWsm[t - NPB * HEADS] = redR;
    __syncthreads();

    // self-loop alpha (w = mean incoming weight from sWsm); self xl row from GLOBAL
    if (t < NPB * HEADS) {
        int nn = nnD, hh = hhD;
        int dg = sStart[nn + 1] - sStart[nn];
        float w = sWsm[nn] / fmaxf((float)dg, 1.0f);
        const uint4* pa = (const uint4*)(xl + (size_t)(n0 + nn) * FEAT + hh * 32);
        const uint4* pb = (const uint4*)&sXR[nn * RS + hh * 16];
        float alpha0 = 0.f, alpha1 = 0.f;
#pragma unroll
        for (int g = 0; g < 4; g++) {
            uint4 a4 = pa[g];
            uint4 b4 = pb[g];
            float4 we0 = *(const float4*)&sWeP[hh * APAD + g * 8];
            float4 we1 = *(const float4*)&sWeP[hh * APAD + g * 8 + 4];
            float4 at0 = *(const float4*)&sAttP[hh * APAD + g * 8];
            float4 at1 = *(const float4*)&sAttP[hh * APAD + g * 8 + 4];
            float wec[8] = {we0.x, we0.y, we0.z, we0.w, we1.x, we1.y, we1.z, we1.w};
            float atc[8] = {at0.x, at0.y, at0.z, at0.w, at1.x, at1.y, at1.z, at1.w};
            unsigned aw[4] = {a4.x, a4.y, a4.z, a4.w};
            unsigned bw[4] = {b4.x, b4.y, b4.z, b4.w};
#pragma unroll
            for (int q = 0; q < 4; q++) {
                float m0 = bu2f((unsigned short)aw[q]) + bu2f((unsigned short)bw[q]) + w * wec[q * 2];
                m0 = fmaxf(m0, NEG_SLOPE * m0);
                alpha0 += m0 * atc[q * 2];
                float m1 = bu2f((unsigned short)(aw[q] >> 16)) + bu2f((unsigned short)(bw[q] >> 16)) + w * wec[q * 2 + 1];
                m1 = fmaxf(m1, NEG_SLOPE * m1);
                alpha1 += m1 * atc[q * 2 + 1];
            }
        }
        sExS[t] = __expf(alpha0 + alpha1);
    }
    __syncthreads();

    // epilogue: self-loop add, divide, residual + bias + relu (self xl from global)
    {
        float bj = bias[t];
#pragma unroll
        for (int nn = 0; nn < NPB; nn++) {
            float exS = sExS[nn * HEADS + h];
            size_t off = (size_t)(n0 + nn) * FEAT + t;
            float xsv = bu2f(xl[off]);
            float num = acc[nn] + exS * xsv;
            float dn  = sDen[nn * HEADS + h] + exS;
            float val = x[off] + bj + num / dn;
            out[off] = (val > 0.f) ? val : 0.f;
        }
    }
}

extern "C" void kernel_launch(void* const* d_in, const int* in_sizes, int n_in,
                              void* d_out, int out_size, void* d_ws, size_t ws_size,
                              hipStream_t stream) {
    const float* x    = (const float*)d_in[0];
    const int*   ei   = (const int*)d_in[1];
    const float* ew   = (const float*)d_in[2];
    const float* Wl   = (const float*)d_in[3];
    const float* bl   = (const float*)d_in[4];
    const float* Wr   = (const float*)d_in[5];
    const float* br   = (const float*)d_in[6];
    const float* We   = (const float*)d_in[7];
    const float* att  = (const float*)d_in[8];
    const float* bias = (const float*)d_in[9];
    float* out = (float*)d_out;

    char* ws = (char*)d_ws;
    unsigned short* xl = (unsigned short*)(ws + XL_OFF);
    unsigned short* xr = (unsigned short*)(ws + XR_OFF);
    short* Wt     = (short*)(ws + WT_OFF);
    float* blr    = (float*)(ws + BLR_OFF);
    int2*  pair   = (int2*)(ws + PAIR_OFF);
    int*   deg    = (int*)(ws + DEG_OFF);
    int*   scan   = (int*)(ws + SCAN_OFF);
    int*   bsums  = (int*)(ws + BSUM_OFF);
    int*   boffs  = (int*)(ws + BOFF_OFF);

    // zero deg; harness poisons ws with 0xAA
    hipMemsetAsync(ws + DEG_OFF, 0, N_NODES * sizeof(int), stream);

    k_count<<<(N_EDGES + 255) / 256, 256, 0, stream>>>(ei, deg, Wl, Wr, bl, br, Wt, blr);
    k_scan1<<<NB_SCAN, 256, 0, stream>>>(deg, scan, bsums);
    k_scan2<<<1, 256, 0, stream>>>(bsums, boffs);

    k_scatgemm<<<SCAT_BLOCKS + GEMM_BLOCKS, 384, 0, stream>>>(ei, ew, scan, boffs, deg,
                                                              pair, x, Wt, blr, xl, xr);

    k_node<<<N_NODES / NPB, 192, 0, stream>>>(x, bias, att, We, scan, boffs,
                                              pair, xl, xr, out);
}

// Round 9
// 273.870 us; speedup vs baseline: 1.2386x; 1.0395x over previous
//
#include <hip/hip_runtime.h>
#include <hip/hip_bf16.h>
#include <math.h>

#define N_NODES 50000
#define N_EDGES 400000
#define HEADS 6
#define DIMS 32
#define FEAT 192
#define NEG_SLOPE 0.2f

typedef __attribute__((ext_vector_type(8))) short short8;
typedef __attribute__((ext_vector_type(4))) float f32x4;

__device__ __forceinline__ unsigned short f2bu(float f) {
    __hip_bfloat16 h = __float2bfloat16(f);
    unsigned short u; __builtin_memcpy(&u, &h, 2); return u;
}
__device__ __forceinline__ float bu2f(unsigned short u) {
    return __uint_as_float(((unsigned)u) << 16);
}

// ---------------- workspace layout (byte offsets) ----------------
#define XL_OFF    0            // ushort N*192 = 19,200,000
#define XR_OFF    19200000     // ushort N*192
#define WT_OFF    38400000     // short 384*192 = 147,456
#define BLR_OFF   38547456     // float 384
#define PAIR_OFF  38548992     // int2 E = 3,200,000
#define DEG_OFF   41748992     // int N = 200,000 (repurposed as write-cursor by k_fix)
#define SCAN_OFF  42148992     // int N
#define BSUM_OFF  42348992     // int 256
#define BOFF_OFF  42350016     // int 256
#define NB_SCAN ((N_NODES + 255) / 256)   // 196

// ---------------- count (1 atomic/edge) + fused weight pack ----------------
__global__ __launch_bounds__(256) void k_count(const int* __restrict__ ei,
                                               int* __restrict__ deg,
                                               const float* __restrict__ Wl,
                                               const float* __restrict__ Wr,
                                               const float* __restrict__ bl,
                                               const float* __restrict__ br,
                                               short* __restrict__ Wt,
                                               float* __restrict__ blr) {
    int e = blockIdx.x * blockDim.x + threadIdx.x;
    if (e < N_EDGES) atomicAdd(&deg[ei[N_EDGES + e]], 1);
    if (e < 384 * FEAT) {   // pack Wt[n][k] = W[k][n] (bf16)
        int n = e / FEAT, k = e - n * FEAT;
        float v = (n < FEAT) ? Wl[k * FEAT + n] : Wr[k * FEAT + (n - FEAT)];
        Wt[n * FEAT + k] = (short)f2bu(v);
    }
    if (e < 384) blr[e] = (e < FEAT) ? bl[e] : br[e - FEAT];
}

__global__ __launch_bounds__(256) void k_scan1(const int* __restrict__ deg,
                                               int* __restrict__ scan,
                                               int* __restrict__ bsums) {
    int t = threadIdx.x;
    int i = blockIdx.x * 256 + t;
    int v = (i < N_NODES) ? deg[i] : 0;
    __shared__ int s[256];
    s[t] = v; __syncthreads();
    for (int off = 1; off < 256; off <<= 1) {
        int u = (t >= off) ? s[t - off] : 0;
        __syncthreads();
        s[t] += u;
        __syncthreads();
    }
    if (i < N_NODES) scan[i] = s[t];   // inclusive within block
    if (t == 255) bsums[blockIdx.x] = s[255];
}

__global__ __launch_bounds__(256) void k_scan2(int* __restrict__ bsums,
                                               int* __restrict__ boffs) {
    int t = threadIdx.x;
    int v = (t < NB_SCAN) ? bsums[t] : 0;
    __shared__ int s[256];
    s[t] = v; __syncthreads();
    for (int off = 1; off < 256; off <<= 1) {
        int u = (t >= off) ? s[t - off] : 0;
        __syncthreads();
        s[t] += u;
        __syncthreads();
    }
    boffs[t] = s[t] - v;   // exclusive block offsets
}

// deg[d] -> global inclusive-end cursor (one coalesced pass; scatter then needs
// ONE random atomic per edge instead of atomic + random scan read)
__global__ __launch_bounds__(256) void k_fix(int* __restrict__ deg,
                                             const int* __restrict__ scan,
                                             const int* __restrict__ boffs) {
    int i = blockIdx.x * 256 + threadIdx.x;
    if (i < N_NODES) deg[i] = boffs[i >> 8] + scan[i];
}

// ---------------- fused scatter + MFMA GEMM (block-range split) ----------------
// GEMM upgraded to 32-row tiles: half the blocks, half the Wt L2 traffic.
#define SCAT_BLOCKS ((N_EDGES + 383) / 384)   // 1042
#define GEMM_BLOCKS ((N_NODES + 31) / 32)     // 1563 (last block: 16-row tail)
#define OSTRIDE 392
#define ASTRIDE 200
__global__ __launch_bounds__(384) void k_scatgemm(const int* __restrict__ ei,
                                                  const float* __restrict__ ew,
                                                  int* __restrict__ deg,
                                                  int2* __restrict__ pair,
                                                  const float* __restrict__ x,
                                                  const short* __restrict__ Wt,
                                                  const float* __restrict__ blr,
                                                  unsigned short* __restrict__ xl,
                                                  unsigned short* __restrict__ xr) {
    __shared__ unsigned short sOut[16 * OSTRIDE];
    __shared__ unsigned short sA[32 * ASTRIDE];
    if (blockIdx.x < SCAT_BLOCKS) {
        int e = blockIdx.x * 384 + threadIdx.x;
        if (e < N_EDGES) {
            int d = ei[N_EDGES + e];
            int old = atomicSub(&deg[d], 1);     // deg = inclusive-end cursor
            int2 p; p.x = ei[e]; p.y = __float_as_int(ew[e]);
            pair[old - 1] = p;
        }
        return;
    }
    size_t row0 = (size_t)(blockIdx.x - SCAT_BLOCKS) * 32;

    // ---- stage A tile: 32 rows x 192 floats -> bf16 in LDS (2 segs/thread)
#pragma unroll
    for (int s = 0; s < 2; s++) {
        int q = threadIdx.x + s * 384;
        int row = q / 24, k0 = (q - row * 24) * 8;
        size_t gr = row0 + row;
        const float* ap = x + (gr < N_NODES ? gr : row0) * FEAT + k0;  // safe dummy
        float4 v0 = *(const float4*)ap;
        float4 v1 = *(const float4*)(ap + 4);
        unsigned short tmp[8];
        tmp[0] = f2bu(v0.x); tmp[1] = f2bu(v0.y); tmp[2] = f2bu(v0.z); tmp[3] = f2bu(v0.w);
        tmp[4] = f2bu(v1.x); tmp[5] = f2bu(v1.y); tmp[6] = f2bu(v1.z); tmp[7] = f2bu(v1.w);
        int kw = (k0 >> 1) ^ ((row & 7) << 2);
        *(uint4*)&sA[row * ASTRIDE + kw * 2] = *(const uint4*)tmp;
    }
    __syncthreads();

    int wv   = threadIdx.x >> 6;
    int lane = threadIdx.x & 63;
    int m    = lane & 15;
    int kg   = lane >> 4;
    int ncol0 = wv * 64;

    f32x4 acc[2][4];
#pragma unroll
    for (int r = 0; r < 2; r++)
#pragma unroll
        for (int j = 0; j < 4; j++) acc[r][j] = (f32x4){0.f, 0.f, 0.f, 0.f};

#pragma unroll
    for (int ks = 0; ks < 6; ks++) {
        int kb = ks * 32 + kg * 8;
        int kw = (kb >> 1) ^ ((m & 7) << 2);     // (m+16)&7 == m&7: same swizzle
        short8 af0 = *(const short8*)&sA[m * ASTRIDE + kw * 2];
        short8 af1 = *(const short8*)&sA[(16 + m) * ASTRIDE + kw * 2];
        const short* wp = Wt + (size_t)(ncol0 + m) * FEAT + kb;
        short8 b0 = *(const short8*)(wp);
        short8 b1 = *(const short8*)(wp + 16 * FEAT);
        short8 b2 = *(const short8*)(wp + 32 * FEAT);
        short8 b3 = *(const short8*)(wp + 48 * FEAT);
        acc[0][0] = __builtin_amdgcn_mfma_f32_16x16x32_bf16(af0, b0, acc[0][0], 0, 0, 0);
        acc[0][1] = __builtin_amdgcn_mfma_f32_16x16x32_bf16(af0, b1, acc[0][1], 0, 0, 0);
        acc[0][2] = __builtin_amdgcn_mfma_f32_16x16x32_bf16(af0, b2, acc[0][2], 0, 0, 0);
        acc[0][3] = __builtin_amdgcn_mfma_f32_16x16x32_bf16(af0, b3, acc[0][3], 0, 0, 0);
        acc[1][0] = __builtin_amdgcn_mfma_f32_16x16x32_bf16(af1, b0, acc[1][0], 0, 0, 0);
        acc[1][1] = __builtin_amdgcn_mfma_f32_16x16x32_bf16(af1, b1, acc[1][1], 0, 0, 0);
        acc[1][2] = __builtin_amdgcn_mfma_f32_16x16x32_bf16(af1, b2, acc[1][2], 0, 0, 0);
        acc[1][3] = __builtin_amdgcn_mfma_f32_16x16x32_bf16(af1, b3, acc[1][3], 0, 0, 0);
    }

    // ---- epilogue: two 16-row passes through sOut
#pragma unroll
    for (int pass = 0; pass < 2; pass++) {
        if (pass) __syncthreads();   // copy of prev pass done before overwrite
#pragma unroll
        for (int t4 = 0; t4 < 4; t4++) {
            int cc = ncol0 + t4 * 16 + m;
            float bv = blr[cc];
#pragma unroll
            for (int r = 0; r < 4; r++) {
                sOut[(kg * 4 + r) * OSTRIDE + cc] = f2bu(acc[pass][t4][r] + bv);
            }
        }
        __syncthreads();
        for (int q = threadIdx.x; q < 768; q += 384) {
            int row = q / 48, p = q - row * 48;
            size_t gr = row0 + pass * 16 + row;
            if (gr < N_NODES) {
                uint4 v = *(const uint4*)&sOut[row * OSTRIDE + p * 8];
                if (p < 24) *(uint4*)(xl + gr * FEAT + p * 8) = v;
                else        *(uint4*)(xr + gr * FEAT + (p - 24) * 8) = v;
            }
        }
    }
}

// ---------------- fused node kernel (r3 chassis; in-kernel den+wsm) ----------------
// 8 nodes/block, 192 threads, 32-edge chunks. Closed levers (measured): VALU
// trims, ILP unrolls, MFMA accumulate, coarsening, LDS pipelining — k_node's
// ~95us floor is gather-latency at pinned ~11 waves/CU.
#define NPB 8
#define CEDGE 32
#define RS 100   // uints per row; rows 16B aligned; 100 % 32 = 4 spreads banks
#define APAD 36  // att/We row stride (float4-aligned)
__global__ __launch_bounds__(192) void k_node(const float* __restrict__ x,
                                              const float* __restrict__ bias,
                                              const float* __restrict__ att,
                                              const float* __restrict__ We,
                                              const int* __restrict__ scan,
                                              const int* __restrict__ boffs,
                                              const int2* __restrict__ pair,
                                              const unsigned short* __restrict__ xl,
                                              const unsigned short* __restrict__ xr,
                                              float* __restrict__ out) {
    __shared__ __align__(16) unsigned int sXL[CEDGE * RS];
    __shared__ __align__(16) unsigned int sXR[NPB * RS];
    __shared__ float sEx[CEDGE * HEADS];
    __shared__ float sExS[NPB * HEADS];
    __shared__ int   sSrc[2][CEDGE];
    __shared__ float sW[2][CEDGE];
    __shared__ int   sDst[2][CEDGE];
    __shared__ int   sStart[NPB + 1];
    __shared__ __align__(16) float sAttP[HEADS * APAD];
    __shared__ __align__(16) float sWeP[HEADS * APAD];
    __shared__ float sDen[NPB * HEADS];
    __shared__ float sWsm[NPB];

    int t = threadIdx.x;
    int h = t >> 5;                  // head for channel role
    int n0 = blockIdx.x * NPB;

    int gbase = boffs[n0 >> 8] + ((n0 & 255) ? scan[n0 - 1] : 0);
    int n8 = n0 + NPB;
    int gend = (n8 >= N_NODES) ? N_EDGES
             : (boffs[n8 >> 8] + ((n8 & 255) ? scan[n8 - 1] : 0));
    int etot = gend - gbase;
    int c0 = min(etot, CEDGE);

    if (t < c0) { int2 p = pair[gbase + t]; sSrc[0][t] = p.x; sW[0][t] = __int_as_float(p.y); }

    for (int q = t; q < HEADS * APAD; q += 192) {
        int hh = q / APAD, c = q - hh * APAD;
        if (c < 32) { sAttP[q] = att[hh * 32 + c]; sWeP[q] = We[hh * 32 + c]; }
    }
    if (t <= NPB) {
        int n = n0 + t;
        int st;
        if (n >= N_NODES) st = N_EDGES;
        else {
            int b = n >> 8;
            st = boffs[b] + ((n & 255) ? scan[n - 1] : 0);
        }
        sStart[t] = st;
    }
    if (t < NPB) {   // sDst[0] pre-fill with self-computed bounds (no sStart dep)
        int n = n0 + t;
        int a = boffs[n >> 8] + ((n & 255) ? scan[n - 1] : 0);
        int n1 = n + 1;
        int b = (n1 >= N_NODES) ? N_EDGES
              : (boffs[n1 >> 8] + ((n1 & 255) ? scan[n1 - 1] : 0));
        int lo = a - gbase; if (lo < 0) lo = 0;
        int hi = b - gbase; if (hi > c0) hi = c0;
        for (int q = lo; q < hi; q++) sDst[0][q] = t;
    }
    {   // stage this block's 8 xr rows: 192 = 8 rows x 24 uint4
        int nn = t / 24, p = t - nn * 24;
        *(uint4*)&sXR[nn * RS + p * 4] = ((const uint4*)(xr + (size_t)(n0 + nn) * FEAT))[p];
    }
    __syncthreads();

    float acc[NPB];
#pragma unroll
    for (int nn = 0; nn < NPB; nn++) acc[nn] = 0.f;
    float redR = 0.f;                               // den (t<48) OR wsm (t in [48,56))
    int nnD = t / HEADS, hhD = t - nnD * HEADS;     // den ownership (t < 48)

    int nch = (etot + CEDGE - 1) / CEDGE;
    for (int ci = 0; ci < nch; ci++) {
        int i0 = ci * CEDGE;
        int c  = min(etot - i0, CEDGE);
        int cn = min(etot - i0 - CEDGE, CEDGE);   // next chunk size
        int cb = ci & 1, nb = cb ^ 1;

        // A: gather xl chunk ci -> sXL; overlap: prefetch pair ci+1 -> regs; fill sDst[nb]
        {
            int nld = c * 24;
#pragma unroll
            for (int s = 0; s < 4; s++) {
                int q = t + s * 192;
                if (q < nld) {
                    int i = q / 24, p = q - i * 24;
                    *(uint4*)&sXL[i * RS + p * 4] =
                        *(const uint4*)(xl + (size_t)sSrc[cb][i] * FEAT + p * 8);
                }
            }
        }
        int2 P;
        if (t < cn) P = pair[gbase + i0 + CEDGE + t];
        if (t < NPB && cn > 0) {
            int lo = sStart[t] - gbase - i0 - CEDGE;     if (lo < 0) lo = 0;
            int hi = sStart[t + 1] - gbase - i0 - CEDGE; if (hi > cn) hi = cn;
            for (int q = lo; q < hi; q++) sDst[nb][q] = t;
        }
        __syncthreads();

        // C: alpha + exp for chunk ci; commit pair regs -> sSrc/sW[nb]
        if (t < c * HEADS) {
            int i = t / HEADS, hh = t - i * HEADS;
            int nn = sDst[cb][i];
            float w = sW[cb][i];
            const uint4* pa = (const uint4*)&sXL[i * RS + hh * 16];
            const uint4* pb = (const uint4*)&sXR[nn * RS + hh * 16];
            float alpha0 = 0.f, alpha1 = 0.f;
#pragma unroll
            for (int g = 0; g < 4; g++) {
                uint4 a4 = pa[g];
                uint4 b4 = pb[g];
                float4 we0 = *(const float4*)&sWeP[hh * APAD + g * 8];
                float4 we1 = *(const float4*)&sWeP[hh * APAD + g * 8 + 4];
                float4 at0 = *(const float4*)&sAttP[hh * APAD + g * 8];
                float4 at1 = *(const float4*)&sAttP[hh * APAD + g * 8 + 4];
                float wec[8] = {we0.x, we0.y, we0.z, we0.w, we1.x, we1.y, we1.z, we1.w};
                float atc[8] = {at0.x, at0.y, at0.z, at0.w, at1.x, at1.y, at1.z, at1.w};
                unsigned aw[4] = {a4.x, a4.y, a4.z, a4.w};
                unsigned bw[4] = {b4.x, b4.y, b4.z, b4.w};
#pragma unroll
                for (int q = 0; q < 4; q++) {
                    float m0 = bu2f((unsigned short)aw[q]) + bu2f((unsigned short)bw[q]) + w * wec[q * 2];
                    m0 = fmaxf(m0, NEG_SLOPE * m0);
                    alpha0 += m0 * atc[q * 2];
                    float m1 = bu2f((unsigned short)(aw[q] >> 16)) + bu2f((unsigned short)(bw[q] >> 16)) + w * wec[q * 2 + 1];
                    m1 = fmaxf(m1, NEG_SLOPE * m1);
                    alpha1 += m1 * atc[q * 2 + 1];
                }
            }
            sEx[t] = __expf(alpha0 + alpha1);
        }
        if (t < cn) { sSrc[nb][t] = P.x; sW[nb][t] = __int_as_float(P.y); }
        __syncthreads();

        // E: accumulate (all threads) + den(48 thr) / wsm(8 thr)
        {
            int cw = t >> 1;
#pragma unroll
            for (int nn = 0; nn < NPB; nn++) {
                int lo = sStart[nn] - gbase - i0;     if (lo < 0) lo = 0;
                int hi = sStart[nn + 1] - gbase - i0; if (hi > c) hi = c;
                for (int i = lo; i < hi; i++) {
                    float ex = sEx[i * HEADS + h];
                    unsigned u = sXL[i * RS + cw];
                    unsigned short v = (t & 1) ? (unsigned short)(u >> 16) : (unsigned short)u;
                    acc[nn] += ex * bu2f(v);
                }
            }
            if (t < NPB * HEADS) {
                int lo = sStart[nnD] - gbase - i0;     if (lo < 0) lo = 0;
                int hi = sStart[nnD + 1] - gbase - i0; if (hi > c) hi = c;
                for (int i = lo; i < hi; i++) redR += sEx[i * HEADS + hhD];
            } else if (t < NPB * HEADS + NPB) {
                int nw = t - NPB * HEADS;
                int lo = sStart[nw] - gbase - i0;     if (lo < 0) lo = 0;
                int hi = sStart[nw + 1] - gbase - i0; if (hi > c) hi = c;
                for (int i = lo; i < hi; i++) redR += sW[cb][i];
            }
        }
        __syncthreads();   // protects sXL/sDst overwrite next iter
    }

    if (t < NPB * HEADS) sDen[t] = redR;
    else if (t < NPB * HEADS + NPB) sWsm[t - NPB * HEADS] = redR;
    __syncthreads();

    // self-loop alpha (w = mean incoming weight from sWsm); self xl row from GLOBAL
    if (t < NPB * HEADS) {
        int nn = nnD, hh = hhD;
        int dg = sStart[nn + 1] - sStart[nn];
        float w = sWsm[nn] / fmaxf((float)dg, 1.0f);
        const uint4* pa = (const uint4*)(xl + (size_t)(n0 + nn) * FEAT + hh * 32);
        const uint4* pb = (const uint4*)&sXR[nn * RS + hh * 16];
        float alpha0 = 0.f, alpha1 = 0.f;
#pragma unroll
        for (int g = 0; g < 4; g++) {
            uint4 a4 = pa[g];
            uint4 b4 = pb[g];
            float4 we0 = *(const float4*)&sWeP[hh * APAD + g * 8];
            float4 we1 = *(const float4*)&sWeP[hh * APAD + g * 8 + 4];
            float4 at0 = *(const float4*)&sAttP[hh * APAD + g * 8];
            float4 at1 = *(const float4*)&sAttP[hh * APAD + g * 8 + 4];
            float wec[8] = {we0.x, we0.y, we0.z, we0.w, we1.x, we1.y, we1.z, we1.w};
            float atc[8] = {at0.x, at0.y, at0.z, at0.w, at1.x, at1.y, at1.z, at1.w};
            unsigned aw[4] = {a4.x, a4.y, a4.z, a4.w};
            unsigned bw[4] = {b4.x, b4.y, b4.z, b4.w};
#pragma unroll
            for (int q = 0; q < 4; q++) {
                float m0 = bu2f((unsigned short)aw[q]) + bu2f((unsigned short)bw[q]) + w * wec[q * 2];
                m0 = fmaxf(m0, NEG_SLOPE * m0);
                alpha0 += m0 * atc[q * 2];
                float m1 = bu2f((unsigned short)(aw[q] >> 16)) + bu2f((unsigned short)(bw[q] >> 16)) + w * wec[q * 2 + 1];
                m1 = fmaxf(m1, NEG_SLOPE * m1);
                alpha1 += m1 * atc[q * 2 + 1];
            }
        }
        sExS[t] = __expf(alpha0 + alpha1);
    }
    __syncthreads();

    // epilogue: self-loop add, divide, residual + bias + relu (self xl from global)
    {
        float bj = bias[t];
#pragma unroll
        for (int nn = 0; nn < NPB; nn++) {
            float exS = sExS[nn * HEADS + h];
            size_t off = (size_t)(n0 + nn) * FEAT + t;
            float xsv = bu2f(xl[off]);
            float num = acc[nn] + exS * xsv;
            float dn  = sDen[nn * HEADS + h] + exS;
            float val = x[off] + bj + num / dn;
            out[off] = (val > 0.f) ? val : 0.f;
        }
    }
}

extern "C" void kernel_launch(void* const* d_in, const int* in_sizes, int n_in,
                              void* d_out, int out_size, void* d_ws, size_t ws_size,
                              hipStream_t stream) {
    const float* x    = (const float*)d_in[0];
    const int*   ei   = (const int*)d_in[1];
    const float* ew   = (const float*)d_in[2];
    const float* Wl   = (const float*)d_in[3];
    const float* bl   = (const float*)d_in[4];
    const float* Wr   = (const float*)d_in[5];
    const float* br   = (const float*)d_in[6];
    const float* We   = (const float*)d_in[7];
    const float* att  = (const float*)d_in[8];
    const float* bias = (const float*)d_in[9];
    float* out = (float*)d_out;

    char* ws = (char*)d_ws;
    unsigned short* xl = (unsigned short*)(ws + XL_OFF);
    unsigned short* xr = (unsigned short*)(ws + XR_OFF);
    short* Wt     = (short*)(ws + WT_OFF);
    float* blr    = (float*)(ws + BLR_OFF);
    int2*  pair   = (int2*)(ws + PAIR_OFF);
    int*   deg    = (int*)(ws + DEG_OFF);
    int*   scan   = (int*)(ws + SCAN_OFF);
    int*   bsums  = (int*)(ws + BSUM_OFF);
    int*   boffs  = (int*)(ws + BOFF_OFF);

    // zero deg; harness poisons ws with 0xAA
    hipMemsetAsync(ws + DEG_OFF, 0, N_NODES * sizeof(int), stream);

    k_count<<<(N_EDGES + 255) / 256, 256, 0, stream>>>(ei, deg, Wl, Wr, bl, br, Wt, blr);
    k_scan1<<<NB_SCAN, 256, 0, stream>>>(deg, scan, bsums);
    k_scan2<<<1, 256, 0, stream>>>(bsums, boffs);
    k_fix<<<NB_SCAN, 256, 0, stream>>>(deg, scan, boffs);

    k_scatgemm<<<SCAT_BLOCKS + GEMM_BLOCKS, 384, 0, stream>>>(ei, ew, deg, pair,
                                                              x, Wt, blr, xl, xr);

    k_node<<<N_NODES / NPB, 192, 0, stream>>>(x, bias, att, We, scan, boffs,
                                              pair, xl, xr, out);
}

// Round 10
// 259.474 us; speedup vs baseline: 1.3074x; 1.0555x over previous
//
#include <hip/hip_runtime.h>
#include <hip/hip_bf16.h>
#include <math.h>

#define N_NODES 50000
#define N_EDGES 400000
#define HEADS 6
#define DIMS 32
#define FEAT 192
#define NEG_SLOPE 0.2f

typedef __attribute__((ext_vector_type(8))) short short8;
typedef __attribute__((ext_vector_type(4))) float f32x4;

__device__ __forceinline__ unsigned short f2bu(float f) {
    __hip_bfloat16 h = __float2bfloat16(f);
    unsigned short u; __builtin_memcpy(&u, &h, 2); return u;
}
__device__ __forceinline__ float bu2f(unsigned short u) {
    return __uint_as_float(((unsigned)u) << 16);
}

// ---------------- workspace layout (byte offsets) ----------------
#define XL_OFF    0            // ushort N*192 = 19,200,000
#define XR_OFF    19200000     // ushort N*192
#define WT_OFF    38400000     // short 384*192 = 147,456
#define BLR_OFF   38547456     // float 384
#define PAIR_OFF  38548992     // int2 E = 3,200,000
#define DEG_OFF   41748992     // int N (counts -> exclusive starts via k_fix)
#define SCAN_OFF  42148992     // int N
#define BSUM_OFF  42348992     // int 256
#define BOFF_OFF  42350016     // int 256
#define RANK_OFF  42351040     // int E = 1,600,000 (per-edge rank within dst)
#define NB_SCAN ((N_NODES + 255) / 256)   // 196

// ---------------- count (1 atomic/edge, rank persisted) + weight pack ----------------
__global__ __launch_bounds__(256) void k_count(const int* __restrict__ ei,
                                               int* __restrict__ deg,
                                               int* __restrict__ rank,
                                               const float* __restrict__ Wl,
                                               const float* __restrict__ Wr,
                                               const float* __restrict__ bl,
                                               const float* __restrict__ br,
                                               short* __restrict__ Wt,
                                               float* __restrict__ blr) {
    int e = blockIdx.x * blockDim.x + threadIdx.x;
    if (e < N_EDGES) rank[e] = atomicAdd(&deg[ei[N_EDGES + e]], 1);
    if (e < 384 * FEAT) {   // pack Wt[n][k] = W[k][n] (bf16)
        int n = e / FEAT, k = e - n * FEAT;
        float v = (n < FEAT) ? Wl[k * FEAT + n] : Wr[k * FEAT + (n - FEAT)];
        Wt[n * FEAT + k] = (short)f2bu(v);
    }
    if (e < 384) blr[e] = (e < FEAT) ? bl[e] : br[e - FEAT];
}

__global__ __launch_bounds__(256) void k_scan1(const int* __restrict__ deg,
                                               int* __restrict__ scan,
                                               int* __restrict__ bsums) {
    int t = threadIdx.x;
    int i = blockIdx.x * 256 + t;
    int v = (i < N_NODES) ? deg[i] : 0;
    __shared__ int s[256];
    s[t] = v; __syncthreads();
    for (int off = 1; off < 256; off <<= 1) {
        int u = (t >= off) ? s[t - off] : 0;
        __syncthreads();
        s[t] += u;
        __syncthreads();
    }
    if (i < N_NODES) scan[i] = s[t];   // inclusive within block
    if (t == 255) bsums[blockIdx.x] = s[255];
}

__global__ __launch_bounds__(256) void k_scan2(int* __restrict__ bsums,
                                               int* __restrict__ boffs) {
    int t = threadIdx.x;
    int v = (t < NB_SCAN) ? bsums[t] : 0;
    __shared__ int s[256];
    s[t] = v; __syncthreads();
    for (int off = 1; off < 256; off <<= 1) {
        int u = (t >= off) ? s[t - off] : 0;
        __syncthreads();
        s[t] += u;
        __syncthreads();
    }
    boffs[t] = s[t] - v;   // exclusive block offsets
}

// deg[d]: count -> EXCLUSIVE start (one coalesced pass). Scatter then needs
// zero atomics: slot = deg[d] + rank[e] (random READ instead of random atomic).
__global__ __launch_bounds__(256) void k_fix(int* __restrict__ deg,
                                             const int* __restrict__ scan,
                                             const int* __restrict__ boffs) {
    int i = blockIdx.x * 256 + threadIdx.x;
    if (i < N_NODES) deg[i] = boffs[i >> 8] + scan[i] - deg[i];
}

// ---------------- fused scatter + MFMA GEMM (block-range split) ----------------
#define SCAT_BLOCKS ((N_EDGES + 383) / 384)   // 1042
#define GEMM_BLOCKS ((N_NODES + 31) / 32)     // 1563 (last block: 16-row tail)
#define OSTRIDE 392
#define ASTRIDE 200
__global__ __launch_bounds__(384) void k_scatgemm(const int* __restrict__ ei,
                                                  const float* __restrict__ ew,
                                                  const int* __restrict__ deg,
                                                  const int* __restrict__ rank,
                                                  int2* __restrict__ pair,
                                                  const float* __restrict__ x,
                                                  const short* __restrict__ Wt,
                                                  const float* __restrict__ blr,
                                                  unsigned short* __restrict__ xl,
                                                  unsigned short* __restrict__ xr) {
    __shared__ unsigned short sOut[16 * OSTRIDE];
    __shared__ unsigned short sA[32 * ASTRIDE];
    if (blockIdx.x < SCAT_BLOCKS) {
        int e = blockIdx.x * 384 + threadIdx.x;
        if (e < N_EDGES) {
            int d = ei[N_EDGES + e];
            int slot = deg[d] + rank[e];         // atomic-free scatter
            int2 p; p.x = ei[e]; p.y = __float_as_int(ew[e]);
            pair[slot] = p;
        }
        return;
    }
    size_t row0 = (size_t)(blockIdx.x - SCAT_BLOCKS) * 32;

    // ---- stage A tile: 32 rows x 192 floats -> bf16 in LDS (2 segs/thread)
#pragma unroll
    for (int s = 0; s < 2; s++) {
        int q = threadIdx.x + s * 384;
        int row = q / 24, k0 = (q - row * 24) * 8;
        size_t gr = row0 + row;
        const float* ap = x + (gr < N_NODES ? gr : row0) * FEAT + k0;  // safe dummy
        float4 v0 = *(const float4*)ap;
        float4 v1 = *(const float4*)(ap + 4);
        unsigned short tmp[8];
        tmp[0] = f2bu(v0.x); tmp[1] = f2bu(v0.y); tmp[2] = f2bu(v0.z); tmp[3] = f2bu(v0.w);
        tmp[4] = f2bu(v1.x); tmp[5] = f2bu(v1.y); tmp[6] = f2bu(v1.z); tmp[7] = f2bu(v1.w);
        int kw = (k0 >> 1) ^ ((row & 7) << 2);
        *(uint4*)&sA[row * ASTRIDE + kw * 2] = *(const uint4*)tmp;
    }
    __syncthreads();

    int wv   = threadIdx.x >> 6;
    int lane = threadIdx.x & 63;
    int m    = lane & 15;
    int kg   = lane >> 4;
    int ncol0 = wv * 64;

    f32x4 acc[2][4];
#pragma unroll
    for (int r = 0; r < 2; r++)
#pragma unroll
        for (int j = 0; j < 4; j++) acc[r][j] = (f32x4){0.f, 0.f, 0.f, 0.f};

#pragma unroll
    for (int ks = 0; ks < 6; ks++) {
        int kb = ks * 32 + kg * 8;
        int kw = (kb >> 1) ^ ((m & 7) << 2);     // (m+16)&7 == m&7: same swizzle
        short8 af0 = *(const short8*)&sA[m * ASTRIDE + kw * 2];
        short8 af1 = *(const short8*)&sA[(16 + m) * ASTRIDE + kw * 2];
        const short* wp = Wt + (size_t)(ncol0 + m) * FEAT + kb;
        short8 b0 = *(const short8*)(wp);
        short8 b1 = *(const short8*)(wp + 16 * FEAT);
        short8 b2 = *(const short8*)(wp + 32 * FEAT);
        short8 b3 = *(const short8*)(wp + 48 * FEAT);
        acc[0][0] = __builtin_amdgcn_mfma_f32_16x16x32_bf16(af0, b0, acc[0][0], 0, 0, 0);
        acc[0][1] = __builtin_amdgcn_mfma_f32_16x16x32_bf16(af0, b1, acc[0][1], 0, 0, 0);
        acc[0][2] = __builtin_amdgcn_mfma_f32_16x16x32_bf16(af0, b2, acc[0][2], 0, 0, 0);
        acc[0][3] = __builtin_amdgcn_mfma_f32_16x16x32_bf16(af0, b3, acc[0][3], 0, 0, 0);
        acc[1][0] = __builtin_amdgcn_mfma_f32_16x16x32_bf16(af1, b0, acc[1][0], 0, 0, 0);
        acc[1][1] = __builtin_amdgcn_mfma_f32_16x16x32_bf16(af1, b1, acc[1][1], 0, 0, 0);
        acc[1][2] = __builtin_amdgcn_mfma_f32_16x16x32_bf16(af1, b2, acc[1][2], 0, 0, 0);
        acc[1][3] = __builtin_amdgcn_mfma_f32_16x16x32_bf16(af1, b3, acc[1][3], 0, 0, 0);
    }

    // ---- epilogue: two 16-row passes through sOut
#pragma unroll
    for (int pass = 0; pass < 2; pass++) {
        if (pass) __syncthreads();   // copy of prev pass done before overwrite
#pragma unroll
        for (int t4 = 0; t4 < 4; t4++) {
            int cc = ncol0 + t4 * 16 + m;
            float bv = blr[cc];
#pragma unroll
            for (int r = 0; r < 4; r++) {
                sOut[(kg * 4 + r) * OSTRIDE + cc] = f2bu(acc[pass][t4][r] + bv);
            }
        }
        __syncthreads();
        for (int q = threadIdx.x; q < 768; q += 384) {
            int row = q / 48, p = q - row * 48;
            size_t gr = row0 + pass * 16 + row;
            if (gr < N_NODES) {
                uint4 v = *(const uint4*)&sOut[row * OSTRIDE + p * 8];
                if (p < 24) *(uint4*)(xl + gr * FEAT + p * 8) = v;
                else        *(uint4*)(xr + gr * FEAT + (p - 24) * 8) = v;
            }
        }
    }
}

// ---------------- fused node kernel (r3 chassis; in-kernel den+wsm) ----------------
// 8 nodes/block, 192 threads, 32-edge chunks. Closed levers (measured): VALU
// trims, ILP unrolls, MFMA accumulate, coarsening, LDS pipelining — k_node's
// ~95-100us floor is gather-latency at pinned ~11 waves/CU.
#define NPB 8
#define CEDGE 32
#define RS 100   // uints per row; rows 16B aligned; 100 % 32 = 4 spreads banks
#define APAD 36  // att/We row stride (float4-aligned)
__global__ __launch_bounds__(192) void k_node(const float* __restrict__ x,
                                              const float* __restrict__ bias,
                                              const float* __restrict__ att,
                                              const float* __restrict__ We,
                                              const int* __restrict__ scan,
                                              const int* __restrict__ boffs,
                                              const int2* __restrict__ pair,
                                              const unsigned short* __restrict__ xl,
                                              const unsigned short* __restrict__ xr,
                                              float* __restrict__ out) {
    __shared__ __align__(16) unsigned int sXL[CEDGE * RS];
    __shared__ __align__(16) unsigned int sXR[NPB * RS];
    __shared__ float sEx[CEDGE * HEADS];
    __shared__ float sExS[NPB * HEADS];
    __shared__ int   sSrc[2][CEDGE];
    __shared__ float sW[2][CEDGE];
    __shared__ int   sDst[2][CEDGE];
    __shared__ int   sStart[NPB + 1];
    __shared__ __align__(16) float sAttP[HEADS * APAD];
    __shared__ __align__(16) float sWeP[HEADS * APAD];
    __shared__ float sDen[NPB * HEADS];
    __shared__ float sWsm[NPB];

    int t = threadIdx.x;
    int h = t >> 5;                  // head for channel role
    int n0 = blockIdx.x * NPB;

    int gbase = boffs[n0 >> 8] + ((n0 & 255) ? scan[n0 - 1] : 0);
    int n8 = n0 + NPB;
    int gend = (n8 >= N_NODES) ? N_EDGES
             : (boffs[n8 >> 8] + ((n8 & 255) ? scan[n8 - 1] : 0));
    int etot = gend - gbase;
    int c0 = min(etot, CEDGE);

    if (t < c0) { int2 p = pair[gbase + t]; sSrc[0][t] = p.x; sW[0][t] = __int_as_float(p.y); }

    for (int q = t; q < HEADS * APAD; q += 192) {
        int hh = q / APAD, c = q - hh * APAD;
        if (c < 32) { sAttP[q] = att[hh * 32 + c]; sWeP[q] = We[hh * 32 + c]; }
    }
    if (t <= NPB) {
        int n = n0 + t;
        int st;
        if (n >= N_NODES) st = N_EDGES;
        else {
            int b = n >> 8;
            st = boffs[b] + ((n & 255) ? scan[n - 1] : 0);
        }
        sStart[t] = st;
    }
    if (t < NPB) {   // sDst[0] pre-fill with self-computed bounds (no sStart dep)
        int n = n0 + t;
        int a = boffs[n >> 8] + ((n & 255) ? scan[n - 1] : 0);
        int n1 = n + 1;
        int b = (n1 >= N_NODES) ? N_EDGES
              : (boffs[n1 >> 8] + ((n1 & 255) ? scan[n1 - 1] : 0));
        int lo = a - gbase; if (lo < 0) lo = 0;
        int hi = b - gbase; if (hi > c0) hi = c0;
        for (int q = lo; q < hi; q++) sDst[0][q] = t;
    }
    {   // stage this block's 8 xr rows: 192 = 8 rows x 24 uint4
        int nn = t / 24, p = t - nn * 24;
        *(uint4*)&sXR[nn * RS + p * 4] = ((const uint4*)(xr + (size_t)(n0 + nn) * FEAT))[p];
    }
    __syncthreads();

    float acc[NPB];
#pragma unroll
    for (int nn = 0; nn < NPB; nn++) acc[nn] = 0.f;
    float redR = 0.f;                               // den (t<48) OR wsm (t in [48,56))
    int nnD = t / HEADS, hhD = t - nnD * HEADS;     // den ownership (t < 48)

    int nch = (etot + CEDGE - 1) / CEDGE;
    for (int ci = 0; ci < nch; ci++) {
        int i0 = ci * CEDGE;
        int c  = min(etot - i0, CEDGE);
        int cn = min(etot - i0 - CEDGE, CEDGE);   // next chunk size
        int cb = ci & 1, nb = cb ^ 1;

        // A: gather xl chunk ci -> sXL; overlap: prefetch pair ci+1 -> regs; fill sDst[nb]
        {
            int nld = c * 24;
#pragma unroll
            for (int s = 0; s < 4; s++) {
                int q = t + s * 192;
                if (q < nld) {
                    int i = q / 24, p = q - i * 24;
                    *(uint4*)&sXL[i * RS + p * 4] =
                        *(const uint4*)(xl + (size_t)sSrc[cb][i] * FEAT + p * 8);
                }
            }
        }
        int2 P;
        if (t < cn) P = pair[gbase + i0 + CEDGE + t];
        if (t < NPB && cn > 0) {
            int lo = sStart[t] - gbase - i0 - CEDGE;     if (lo < 0) lo = 0;
            int hi = sStart[t + 1] - gbase - i0 - CEDGE; if (hi > cn) hi = cn;
            for (int q = lo; q < hi; q++) sDst[nb][q] = t;
        }
        __syncthreads();

        // C: alpha + exp for chunk ci; commit pair regs -> sSrc/sW[nb]
        if (t < c * HEADS) {
            int i = t / HEADS, hh = t - i * HEADS;
            int nn = sDst[cb][i];
            float w = sW[cb][i];
            const uint4* pa = (const uint4*)&sXL[i * RS + hh * 16];
            const uint4* pb = (const uint4*)&sXR[nn * RS + hh * 16];
            float alpha0 = 0.f, alpha1 = 0.f;
#pragma unroll
            for (int g = 0; g < 4; g++) {
                uint4 a4 = pa[g];
                uint4 b4 = pb[g];
                float4 we0 = *(const float4*)&sWeP[hh * APAD + g * 8];
                float4 we1 = *(const float4*)&sWeP[hh * APAD + g * 8 + 4];
                float4 at0 = *(const float4*)&sAttP[hh * APAD + g * 8];
                float4 at1 = *(const float4*)&sAttP[hh * APAD + g * 8 + 4];
                float wec[8] = {we0.x, we0.y, we0.z, we0.w, we1.x, we1.y, we1.z, we1.w};
                float atc[8] = {at0.x, at0.y, at0.z, at0.w, at1.x, at1.y, at1.z, at1.w};
                unsigned aw[4] = {a4.x, a4.y, a4.z, a4.w};
                unsigned bw[4] = {b4.x, b4.y, b4.z, b4.w};
#pragma unroll
                for (int q = 0; q < 4; q++) {
                    float m0 = bu2f((unsigned short)aw[q]) + bu2f((unsigned short)bw[q]) + w * wec[q * 2];
                    m0 = fmaxf(m0, NEG_SLOPE * m0);
                    alpha0 += m0 * atc[q * 2];
                    float m1 = bu2f((unsigned short)(aw[q] >> 16)) + bu2f((unsigned short)(bw[q] >> 16)) + w * wec[q * 2 + 1];
                    m1 = fmaxf(m1, NEG_SLOPE * m1);
                    alpha1 += m1 * atc[q * 2 + 1];
                }
            }
            sEx[t] = __expf(alpha0 + alpha1);
        }
        if (t < cn) { sSrc[nb][t] = P.x; sW[nb][t] = __int_as_float(P.y); }
        __syncthreads();

        // E: accumulate (all threads) + den(48 thr) / wsm(8 thr)
        {
            int cw = t >> 1;
#pragma unroll
            for (int nn = 0; nn < NPB; nn++) {
                int lo = sStart[nn] - gbase - i0;     if (lo < 0) lo = 0;
                int hi = sStart[nn + 1] - gbase - i0; if (hi > c) hi = c;
                for (int i = lo; i < hi; i++) {
                    float ex = sEx[i * HEADS + h];
                    unsigned u = sXL[i * RS + cw];
                    unsigned short v = (t & 1) ? (unsigned short)(u >> 16) : (unsigned short)u;
                    acc[nn] += ex * bu2f(v);
                }
            }
            if (t < NPB * HEADS) {
                int lo = sStart[nnD] - gbase - i0;     if (lo < 0) lo = 0;
                int hi = sStart[nnD + 1] - gbase - i0; if (hi > c) hi = c;
                for (int i = lo; i < hi; i++) redR += sEx[i * HEADS + hhD];
            } else if (t < NPB * HEADS + NPB) {
                int nw = t - NPB * HEADS;
                int lo = sStart[nw] - gbase - i0;     if (lo < 0) lo = 0;
                int hi = sStart[nw + 1] - gbase - i0; if (hi > c) hi = c;
                for (int i = lo; i < hi; i++) redR += sW[cb][i];
            }
        }
        __syncthreads();   // protects sXL/sDst overwrite next iter
    }

    if (t < NPB * HEADS) sDen[t] = redR;
    else if (t < NPB * HEADS + NPB) sWsm[t - NPB * HEADS] = redR;
    __syncthreads();

    // self-loop alpha (w = mean incoming weight from sWsm); self xl row from GLOBAL
    if (t < NPB * HEADS) {
        int nn = nnD, hh = hhD;
        int dg = sStart[nn + 1] - sStart[nn];
        float w = sWsm[nn] / fmaxf((float)dg, 1.0f);
        const uint4* pa = (const uint4*)(xl + (size_t)(n0 + nn) * FEAT + hh * 32);
        const uint4* pb = (const uint4*)&sXR[nn * RS + hh * 16];
        float alpha0 = 0.f, alpha1 = 0.f;
#pragma unroll
        for (int g = 0; g < 4; g++) {
            uint4 a4 = pa[g];
            uint4 b4 = pb[g];
            float4 we0 = *(const float4*)&sWeP[hh * APAD + g * 8];
            float4 we1 = *(const float4*)&sWeP[hh * APAD + g * 8 + 4];
            float4 at0 = *(const float4*)&sAttP[hh * APAD + g * 8];
            float4 at1 = *(const float4*)&sAttP[hh * APAD + g * 8 + 4];
            float wec[8] = {we0.x, we0.y, we0.z, we0.w, we1.x, we1.y, we1.z, we1.w};
            float atc[8] = {at0.x, at0.y, at0.z, at0.w, at1.x, at1.y, at1.z, at1.w};
            unsigned aw[4] = {a4.x, a4.y, a4.z, a4.w};
            unsigned bw[4] = {b4.x, b4.y, b4.z, b4.w};
#pragma unroll
            for (int q = 0; q < 4; q++) {
                float m0 = bu2f((unsigned short)aw[q]) + bu2f((unsigned short)bw[q]) + w * wec[q * 2];
                m0 = fmaxf(m0, NEG_SLOPE * m0);
                alpha0 += m0 * atc[q * 2];
                float m1 = bu2f((unsigned short)(aw[q] >> 16)) + bu2f((unsigned short)(bw[q] >> 16)) + w * wec[q * 2 + 1];
                m1 = fmaxf(m1, NEG_SLOPE * m1);
                alpha1 += m1 * atc[q * 2 + 1];
            }
        }
        sExS[t] = __expf(alpha0 + alpha1);
    }
    __syncthreads();

    // epilogue: self-loop add, divide, residual + bias + relu (self xl from global)
    {
        float bj = bias[t];
#pragma unroll
        for (int nn = 0; nn < NPB; nn++) {
            float exS = sExS[nn * HEADS + h];
            size_t off = (size_t)(n0 + nn) * FEAT + t;
            float xsv = bu2f(xl[off]);
            float num = acc[nn] + exS * xsv;
            float dn  = sDen[nn * HEADS + h] + exS;
            float val = x[off] + bj + num / dn;
            out[off] = (val > 0.f) ? val : 0.f;
        }
    }
}

extern "C" void kernel_launch(void* const* d_in, const int* in_sizes, int n_in,
                              void* d_out, int out_size, void* d_ws, size_t ws_size,
                              hipStream_t stream) {
    const float* x    = (const float*)d_in[0];
    const int*   ei   = (const int*)d_in[1];
    const float* ew   = (const float*)d_in[2];
    const float* Wl   = (const float*)d_in[3];
    const float* bl   = (const float*)d_in[4];
    const float* Wr   = (const float*)d_in[5];
    const float* br   = (const float*)d_in[6];
    const float* We   = (const float*)d_in[7];
    const float* att  = (const float*)d_in[8];
    const float* bias = (const float*)d_in[9];
    float* out = (float*)d_out;

    char* ws = (char*)d_ws;
    unsigned short* xl = (unsigned short*)(ws + XL_OFF);
    unsigned short* xr = (unsigned short*)(ws + XR_OFF);
    short* Wt     = (short*)(ws + WT_OFF);
    float* blr    = (float*)(ws + BLR_OFF);
    int2*  pair   = (int2*)(ws + PAIR_OFF);
    int*   deg    = (int*)(ws + DEG_OFF);
    int*   scan   = (int*)(ws + SCAN_OFF);
    int*   bsums  = (int*)(ws + BSUM_OFF);
    int*   boffs  = (int*)(ws + BOFF_OFF);
    int*   rank   = (int*)(ws + RANK_OFF);

    // zero deg; harness poisons ws with 0xAA
    hipMemsetAsync(ws + DEG_OFF, 0, N_NODES * sizeof(int), stream);

    k_count<<<(N_EDGES + 255) / 256, 256, 0, stream>>>(ei, deg, rank, Wl, Wr, bl, br, Wt, blr);
    k_scan1<<<NB_SCAN, 256, 0, stream>>>(deg, scan, bsums);
    k_scan2<<<1, 256, 0, stream>>>(bsums, boffs);
    k_fix<<<NB_SCAN, 256, 0, stream>>>(deg, scan, boffs);

    k_scatgemm<<<SCAT_BLOCKS + GEMM_BLOCKS, 384, 0, stream>>>(ei, ew, deg, rank, pair,
                                                              x, Wt, blr, xl, xr);

    k_node<<<N_NODES / NPB, 192, 0, stream>>>(x, bias, att, We, scan, boffs,
                                              pair, xl, xr, out);
}

// Round 11
// 256.471 us; speedup vs baseline: 1.3227x; 1.0117x over previous
//
#include <hip/hip_runtime.h>
#include <hip/hip_bf16.h>
#include <math.h>

#define N_NODES 50000
#define N_EDGES 400000
#define HEADS 6
#define DIMS 32
#define FEAT 192
#define NEG_SLOPE 0.2f

typedef __attribute__((ext_vector_type(8))) short short8;
typedef __attribute__((ext_vector_type(4))) float f32x4;

__device__ __forceinline__ unsigned short f2bu(float f) {
    __hip_bfloat16 h = __float2bfloat16(f);
    unsigned short u; __builtin_memcpy(&u, &h, 2); return u;
}
__device__ __forceinline__ float bu2f(unsigned short u) {
    return __uint_as_float(((unsigned)u) << 16);
}

// ---------------- workspace layout (byte offsets) ----------------
#define XL_OFF    0            // ushort N*192 = 19,200,000
#define XR_OFF    19200000     // ushort N*192
#define WT_OFF    38400000     // short 384*192 = 147,456
#define BLR_OFF   38547456     // float 384
#define PAIR_OFF  38548992     // int2 E = 3,200,000
#define DEG_OFF   41748992     // int N (counts -> exclusive starts via k_fix)
#define SCAN_OFF  42148992     // int N
#define BSUM_OFF  42348992     // int 256
#define BOFF_OFF  42350016     // int 256
#define RANK_OFF  42351040     // int E = 1,600,000 (per-edge rank within dst)
#define NB_SCAN ((N_NODES + 255) / 256)   // 196

// ---------------- count (1 atomic/edge, rank persisted) + weight pack ----------------
__global__ __launch_bounds__(256) void k_count(const int* __restrict__ ei,
                                               int* __restrict__ deg,
                                               int* __restrict__ rank,
                                               const float* __restrict__ Wl,
                                               const float* __restrict__ Wr,
                                               const float* __restrict__ bl,
                                               const float* __restrict__ br,
                                               short* __restrict__ Wt,
                                               float* __restrict__ blr) {
    int e = blockIdx.x * blockDim.x + threadIdx.x;
    if (e < N_EDGES) rank[e] = atomicAdd(&deg[ei[N_EDGES + e]], 1);
    if (e < 384 * FEAT) {   // pack Wt[n][k] = W[k][n] (bf16)
        int n = e / FEAT, k = e - n * FEAT;
        float v = (n < FEAT) ? Wl[k * FEAT + n] : Wr[k * FEAT + (n - FEAT)];
        Wt[n * FEAT + k] = (short)f2bu(v);
    }
    if (e < 384) blr[e] = (e < FEAT) ? bl[e] : br[e - FEAT];
}

__global__ __launch_bounds__(256) void k_scan1(const int* __restrict__ deg,
                                               int* __restrict__ scan,
                                               int* __restrict__ bsums) {
    int t = threadIdx.x;
    int i = blockIdx.x * 256 + t;
    int v = (i < N_NODES) ? deg[i] : 0;
    __shared__ int s[256];
    s[t] = v; __syncthreads();
    for (int off = 1; off < 256; off <<= 1) {
        int u = (t >= off) ? s[t - off] : 0;
        __syncthreads();
        s[t] += u;
        __syncthreads();
    }
    if (i < N_NODES) scan[i] = s[t];   // inclusive within block
    if (t == 255) bsums[blockIdx.x] = s[255];
}

__global__ __launch_bounds__(256) void k_scan2(int* __restrict__ bsums,
                                               int* __restrict__ boffs) {
    int t = threadIdx.x;
    int v = (t < NB_SCAN) ? bsums[t] : 0;
    __shared__ int s[256];
    s[t] = v; __syncthreads();
    for (int off = 1; off < 256; off <<= 1) {
        int u = (t >= off) ? s[t - off] : 0;
        __syncthreads();
        s[t] += u;
        __syncthreads();
    }
    boffs[t] = s[t] - v;   // exclusive block offsets
}

// deg[d]: count -> EXCLUSIVE start (one coalesced pass). Scatter then needs
// zero atomics: slot = deg[d] + rank[e] (random READ instead of random atomic).
__global__ __launch_bounds__(256) void k_fix(int* __restrict__ deg,
                                             const int* __restrict__ scan,
                                             const int* __restrict__ boffs) {
    int i = blockIdx.x * 256 + threadIdx.x;
    if (i < N_NODES) deg[i] = boffs[i >> 8] + scan[i] - deg[i];
}

// ---------------- fused scatter + MFMA GEMM (block-range split) ----------------
// GEMM upgraded to 64-row tiles: 782 blocks (was 1563), Wt L2 traffic halved,
// per-block fixed costs (stage latency, barriers, epilogue) amortized 2x.
#define SCAT_BLOCKS ((N_EDGES + 383) / 384)   // 1042
#define GEMM_BLOCKS ((N_NODES + 63) / 64)     // 782 (last block: 16-row tail)
#define OSTRIDE 392
#define ASTRIDE 200
__global__ __launch_bounds__(384) void k_scatgemm(const int* __restrict__ ei,
                                                  const float* __restrict__ ew,
                                                  const int* __restrict__ deg,
                                                  const int* __restrict__ rank,
                                                  int2* __restrict__ pair,
                                                  const float* __restrict__ x,
                                                  const short* __restrict__ Wt,
                                                  const float* __restrict__ blr,
                                                  unsigned short* __restrict__ xl,
                                                  unsigned short* __restrict__ xr) {
    __shared__ unsigned short sOut[16 * OSTRIDE];
    __shared__ unsigned short sA[64 * ASTRIDE];
    if (blockIdx.x < SCAT_BLOCKS) {
        int e = blockIdx.x * 384 + threadIdx.x;
        if (e < N_EDGES) {
            int d = ei[N_EDGES + e];
            int slot = deg[d] + rank[e];         // atomic-free scatter
            int2 p; p.x = ei[e]; p.y = __float_as_int(ew[e]);
            pair[slot] = p;
        }
        return;
    }
    size_t row0 = (size_t)(blockIdx.x - SCAT_BLOCKS) * 64;

    // ---- stage A tile: 64 rows x 192 floats -> bf16 in LDS (4 segs/thread)
#pragma unroll
    for (int s = 0; s < 4; s++) {
        int q = threadIdx.x + s * 384;
        int row = q / 24, k0 = (q - row * 24) * 8;
        size_t gr = row0 + row;
        const float* ap = x + (gr < N_NODES ? gr : row0) * FEAT + k0;  // safe dummy
        float4 v0 = *(const float4*)ap;
        float4 v1 = *(const float4*)(ap + 4);
        unsigned short tmp[8];
        tmp[0] = f2bu(v0.x); tmp[1] = f2bu(v0.y); tmp[2] = f2bu(v0.z); tmp[3] = f2bu(v0.w);
        tmp[4] = f2bu(v1.x); tmp[5] = f2bu(v1.y); tmp[6] = f2bu(v1.z); tmp[7] = f2bu(v1.w);
        int kw = (k0 >> 1) ^ ((row & 7) << 2);
        *(uint4*)&sA[row * ASTRIDE + kw * 2] = *(const uint4*)tmp;
    }
    __syncthreads();

    int wv   = threadIdx.x >> 6;
    int lane = threadIdx.x & 63;
    int m    = lane & 15;
    int kg   = lane >> 4;
    int ncol0 = wv * 64;

    f32x4 acc[4][4];   // [row-subtile][col-subtile]
#pragma unroll
    for (int r = 0; r < 4; r++)
#pragma unroll
        for (int j = 0; j < 4; j++) acc[r][j] = (f32x4){0.f, 0.f, 0.f, 0.f};

#pragma unroll
    for (int ks = 0; ks < 6; ks++) {
        int kb = ks * 32 + kg * 8;
        int kw = (kb >> 1) ^ ((m & 7) << 2);     // (m+16k)&7 == m&7: same swizzle
        short8 af0 = *(const short8*)&sA[m * ASTRIDE + kw * 2];
        short8 af1 = *(const short8*)&sA[(16 + m) * ASTRIDE + kw * 2];
        short8 af2 = *(const short8*)&sA[(32 + m) * ASTRIDE + kw * 2];
        short8 af3 = *(const short8*)&sA[(48 + m) * ASTRIDE + kw * 2];
        const short* wp = Wt + (size_t)(ncol0 + m) * FEAT + kb;
#pragma unroll
        for (int j = 0; j < 4; j++) {            // one B tile live at a time
            short8 b = *(const short8*)(wp + j * 16 * FEAT);
            acc[0][j] = __builtin_amdgcn_mfma_f32_16x16x32_bf16(af0, b, acc[0][j], 0, 0, 0);
            acc[1][j] = __builtin_amdgcn_mfma_f32_16x16x32_bf16(af1, b, acc[1][j], 0, 0, 0);
            acc[2][j] = __builtin_amdgcn_mfma_f32_16x16x32_bf16(af2, b, acc[2][j], 0, 0, 0);
            acc[3][j] = __builtin_amdgcn_mfma_f32_16x16x32_bf16(af3, b, acc[3][j], 0, 0, 0);
        }
    }

    // ---- epilogue: four 16-row passes through sOut
#pragma unroll
    for (int pass = 0; pass < 4; pass++) {
        if (pass) __syncthreads();   // prev pass copy done before overwrite
#pragma unroll
        for (int t4 = 0; t4 < 4; t4++) {
            int cc = ncol0 + t4 * 16 + m;
            float bv = blr[cc];
#pragma unroll
            for (int r = 0; r < 4; r++) {
                sOut[(kg * 4 + r) * OSTRIDE + cc] = f2bu(acc[pass][t4][r] + bv);
            }
        }
        __syncthreads();
        for (int q = threadIdx.x; q < 768; q += 384) {
            int row = q / 48, p = q - row * 48;
            size_t gr = row0 + pass * 16 + row;
            if (gr < N_NODES) {
                uint4 v = *(const uint4*)&sOut[row * OSTRIDE + p * 8];
                if (p < 24) *(uint4*)(xl + gr * FEAT + p * 8) = v;
                else        *(uint4*)(xr + gr * FEAT + (p - 24) * 8) = v;
            }
        }
    }
}

// ---------------- fused node kernel (r3 chassis; in-kernel den+wsm) ----------------
// 8 nodes/block, 192 threads, 32-edge chunks. Closed levers (measured): VALU
// trims, ILP unrolls, MFMA accumulate, coarsening, LDS pipelining — k_node's
// ~95-100us floor is gather-latency at pinned ~11 waves/CU.
#define NPB 8
#define CEDGE 32
#define RS 100   // uints per row; rows 16B aligned; 100 % 32 = 4 spreads banks
#define APAD 36  // att/We row stride (float4-aligned)
__global__ __launch_bounds__(192) void k_node(const float* __restrict__ x,
                                              const float* __restrict__ bias,
                                              const float* __restrict__ att,
                                              const float* __restrict__ We,
                                              const int* __restrict__ scan,
                                              const int* __restrict__ boffs,
                                              const int2* __restrict__ pair,
                                              const unsigned short* __restrict__ xl,
                                              const unsigned short* __restrict__ xr,
                                              float* __restrict__ out) {
    __shared__ __align__(16) unsigned int sXL[CEDGE * RS];
    __shared__ __align__(16) unsigned int sXR[NPB * RS];
    __shared__ float sEx[CEDGE * HEADS];
    __shared__ float sExS[NPB * HEADS];
    __shared__ int   sSrc[2][CEDGE];
    __shared__ float sW[2][CEDGE];
    __shared__ int   sDst[2][CEDGE];
    __shared__ int   sStart[NPB + 1];
    __shared__ __align__(16) float sAttP[HEADS * APAD];
    __shared__ __align__(16) float sWeP[HEADS * APAD];
    __shared__ float sDen[NPB * HEADS];
    __shared__ float sWsm[NPB];

    int t = threadIdx.x;
    int h = t >> 5;                  // head for channel role
    int n0 = blockIdx.x * NPB;

    int gbase = boffs[n0 >> 8] + ((n0 & 255) ? scan[n0 - 1] : 0);
    int n8 = n0 + NPB;
    int gend = (n8 >= N_NODES) ? N_EDGES
             : (boffs[n8 >> 8] + ((n8 & 255) ? scan[n8 - 1] : 0));
    int etot = gend - gbase;
    int c0 = min(etot, CEDGE);

    if (t < c0) { int2 p = pair[gbase + t]; sSrc[0][t] = p.x; sW[0][t] = __int_as_float(p.y); }

    for (int q = t; q < HEADS * APAD; q += 192) {
        int hh = q / APAD, c = q - hh * APAD;
        if (c < 32) { sAttP[q] = att[hh * 32 + c]; sWeP[q] = We[hh * 32 + c]; }
    }
    if (t <= NPB) {
        int n = n0 + t;
        int st;
        if (n >= N_NODES) st = N_EDGES;
        else {
            int b = n >> 8;
            st = boffs[b] + ((n & 255) ? scan[n - 1] : 0);
        }
        sStart[t] = st;
    }
    if (t < NPB) {   // sDst[0] pre-fill with self-computed bounds (no sStart dep)
        int n = n0 + t;
        int a = boffs[n >> 8] + ((n & 255) ? scan[n - 1] : 0);
        int n1 = n + 1;
        int b = (n1 >= N_NODES) ? N_EDGES
              : (boffs[n1 >> 8] + ((n1 & 255) ? scan[n1 - 1] : 0));
        int lo = a - gbase; if (lo < 0) lo = 0;
        int hi = b - gbase; if (hi > c0) hi = c0;
        for (int q = lo; q < hi; q++) sDst[0][q] = t;
    }
    {   // stage this block's 8 xr rows: 192 = 8 rows x 24 uint4
        int nn = t / 24, p = t - nn * 24;
        *(uint4*)&sXR[nn * RS + p * 4] = ((const uint4*)(xr + (size_t)(n0 + nn) * FEAT))[p];
    }
    __syncthreads();

    float acc[NPB];
#pragma unroll
    for (int nn = 0; nn < NPB; nn++) acc[nn] = 0.f;
    float redR = 0.f;                               // den (t<48) OR wsm (t in [48,56))
    int nnD = t / HEADS, hhD = t - nnD * HEADS;     // den ownership (t < 48)

    int nch = (etot + CEDGE - 1) / CEDGE;
    for (int ci = 0; ci < nch; ci++) {
        int i0 = ci * CEDGE;
        int c  = min(etot - i0, CEDGE);
        int cn = min(etot - i0 - CEDGE, CEDGE);   // next chunk size
        int cb = ci & 1, nb = cb ^ 1;

        // A: gather xl chunk ci -> sXL; overlap: prefetch pair ci+1 -> regs; fill sDst[nb]
        {
            int nld = c * 24;
#pragma unroll
            for (int s = 0; s < 4; s++) {
                int q = t + s * 192;
                if (q < nld) {
                    int i = q / 24, p = q - i * 24;
                    *(uint4*)&sXL[i * RS + p * 4] =
                        *(const uint4*)(xl + (size_t)sSrc[cb][i] * FEAT + p * 8);
                }
            }
        }
        int2 P;
        if (t < cn) P = pair[gbase + i0 + CEDGE + t];
        if (t < NPB && cn > 0) {
            int lo = sStart[t] - gbase - i0 - CEDGE;     if (lo < 0) lo = 0;
            int hi = sStart[t + 1] - gbase - i0 - CEDGE; if (hi > cn) hi = cn;
            for (int q = lo; q < hi; q++) sDst[nb][q] = t;
        }
        __syncthreads();

        // C: alpha + exp for chunk ci; commit pair regs -> sSrc/sW[nb]
        if (t < c * HEADS) {
            int i = t / HEADS, hh = t - i * HEADS;
            int nn = sDst[cb][i];
            float w = sW[cb][i];
            const uint4* pa = (const uint4*)&sXL[i * RS + hh * 16];
            const uint4* pb = (const uint4*)&sXR[nn * RS + hh * 16];
            float alpha0 = 0.f, alpha1 = 0.f;
#pragma unroll
            for (int g = 0; g < 4; g++) {
                uint4 a4 = pa[g];
                uint4 b4 = pb[g];
                float4 we0 = *(const float4*)&sWeP[hh * APAD + g * 8];
                float4 we1 = *(const float4*)&sWeP[hh * APAD + g * 8 + 4];
                float4 at0 = *(const float4*)&sAttP[hh * APAD + g * 8];
                float4 at1 = *(const float4*)&sAttP[hh * APAD + g * 8 + 4];
                float wec[8] = {we0.x, we0.y, we0.z, we0.w, we1.x, we1.y, we1.z, we1.w};
                float atc[8] = {at0.x, at0.y, at0.z, at0.w, at1.x, at1.y, at1.z, at1.w};
                unsigned aw[4] = {a4.x, a4.y, a4.z, a4.w};
                unsigned bw[4] = {b4.x, b4.y, b4.z, b4.w};
#pragma unroll
                for (int q = 0; q < 4; q++) {
                    float m0 = bu2f((unsigned short)aw[q]) + bu2f((unsigned short)bw[q]) + w * wec[q * 2];
                    m0 = fmaxf(m0, NEG_SLOPE * m0);
                    alpha0 += m0 * atc[q * 2];
                    float m1 = bu2f((unsigned short)(aw[q] >> 16)) + bu2f((unsigned short)(bw[q] >> 16)) + w * wec[q * 2 + 1];
                    m1 = fmaxf(m1, NEG_SLOPE * m1);
                    alpha1 += m1 * atc[q * 2 + 1];
                }
            }
            sEx[t] = __expf(alpha0 + alpha1);
        }
        if (t < cn) { sSrc[nb][t] = P.x; sW[nb][t] = __int_as_float(P.y); }
        __syncthreads();

        // E: accumulate (all threads) + den(48 thr) / wsm(8 thr)
        {
            int cw = t >> 1;
#pragma unroll
            for (int nn = 0; nn < NPB; nn++) {
                int lo = sStart[nn] - gbase - i0;     if (lo < 0) lo = 0;
                int hi = sStart[nn + 1] - gbase - i0; if (hi > c) hi = c;
                for (int i = lo; i < hi; i++) {
                    float ex = sEx[i * HEADS + h];
                    unsigned u = sXL[i * RS + cw];
                    unsigned short v = (t & 1) ? (unsigned short)(u >> 16) : (unsigned short)u;
                    acc[nn] += ex * bu2f(v);
                }
            }
            if (t < NPB * HEADS) {
                int lo = sStart[nnD] - gbase - i0;     if (lo < 0) lo = 0;
                int hi = sStart[nnD + 1] - gbase - i0; if (hi > c) hi = c;
                for (int i = lo; i < hi; i++) redR += sEx[i * HEADS + hhD];
            } else if (t < NPB * HEADS + NPB) {
                int nw = t - NPB * HEADS;
                int lo = sStart[nw] - gbase - i0;     if (lo < 0) lo = 0;
                int hi = sStart[nw + 1] - gbase - i0; if (hi > c) hi = c;
                for (int i = lo; i < hi; i++) redR += sW[cb][i];
            }
        }
        __syncthreads();   // protects sXL/sDst overwrite next iter
    }

    if (t < NPB * HEADS) sDen[t] = redR;
    else if (t < NPB * HEADS + NPB) sWsm[t - NPB * HEADS] = redR;
    __syncthreads();

    // self-loop alpha (w = mean incoming weight from sWsm); self xl row from GLOBAL
    if (t < NPB * HEADS) {
        int nn = nnD, hh = hhD;
        int dg = sStart[nn + 1] - sStart[nn];
        float w = sWsm[nn] / fmaxf((float)dg, 1.0f);
        const uint4* pa = (const uint4*)(xl + (size_t)(n0 + nn) * FEAT + hh * 32);
        const uint4* pb = (const uint4*)&sXR[nn * RS + hh * 16];
        float alpha0 = 0.f, alpha1 = 0.f;
#pragma unroll
        for (int g = 0; g < 4; g++) {
            uint4 a4 = pa[g];
            uint4 b4 = pb[g];
            float4 we0 = *(const float4*)&sWeP[hh * APAD + g * 8];
            float4 we1 = *(const float4*)&sWeP[hh * APAD + g * 8 + 4];
            float4 at0 = *(const float4*)&sAttP[hh * APAD + g * 8];
            float4 at1 = *(const float4*)&sAttP[hh * APAD + g * 8 + 4];
            float wec[8] = {we0.x, we0.y, we0.z, we0.w, we1.x, we1.y, we1.z, we1.w};
            float atc[8] = {at0.x, at0.y, at0.z, at0.w, at1.x, at1.y, at1.z, at1.w};
            unsigned aw[4] = {a4.x, a4.y, a4.z, a4.w};
            unsigned bw[4] = {b4.x, b4.y, b4.z, b4.w};
#pragma unroll
            for (int q = 0; q < 4; q++) {
                float m0 = bu2f((unsigned short)aw[q]) + bu2f((unsigned short)bw[q]) + w * wec[q * 2];
                m0 = fmaxf(m0, NEG_SLOPE * m0);
                alpha0 += m0 * atc[q * 2];
                float m1 = bu2f((unsigned short)(aw[q] >> 16)) + bu2f((unsigned short)(bw[q] >> 16)) + w * wec[q * 2 + 1];
                m1 = fmaxf(m1, NEG_SLOPE * m1);
                alpha1 += m1 * atc[q * 2 + 1];
            }
        }
        sExS[t] = __expf(alpha0 + alpha1);
    }
    __syncthreads();

    // epilogue: self-loop add, divide, residual + bias + relu (self xl from global)
    {
        float bj = bias[t];
#pragma unroll
        for (int nn = 0; nn < NPB; nn++) {
            float exS = sExS[nn * HEADS + h];
            size_t off = (size_t)(n0 + nn) * FEAT + t;
            float xsv = bu2f(xl[off]);
            float num = acc[nn] + exS * xsv;
            float dn  = sDen[nn * HEADS + h] + exS;
            float val = x[off] + bj + num / dn;
            out[off] = (val > 0.f) ? val : 0.f;
        }
    }
}

extern "C" void kernel_launch(void* const* d_in, const int* in_sizes, int n_in,
                              void* d_out, int out_size, void* d_ws, size_t ws_size,
                              hipStream_t stream) {
    const float* x    = (const float*)d_in[0];
    const int*   ei   = (const int*)d_in[1];
    const float* ew   = (const float*)d_in[2];
    const float* Wl   = (const float*)d_in[3];
    const float* bl   = (const float*)d_in[4];
    const float* Wr   = (const float*)d_in[5];
    const float* br   = (const float*)d_in[6];
    const float* We   = (const float*)d_in[7];
    const float* att  = (const float*)d_in[8];
    const float* bias = (const float*)d_in[9];
    float* out = (float*)d_out;

    char* ws = (char*)d_ws;
    unsigned short* xl = (unsigned short*)(ws + XL_OFF);
    unsigned short* xr = (unsigned short*)(ws + XR_OFF);
    short* Wt     = (short*)(ws + WT_OFF);
    float* blr    = (float*)(ws + BLR_OFF);
    int2*  pair   = (int2*)(ws + PAIR_OFF);
    int*   deg    = (int*)(ws + DEG_OFF);
    int*   scan   = (int*)(ws + SCAN_OFF);
    int*   bsums  = (int*)(ws + BSUM_OFF);
    int*   boffs  = (int*)(ws + BOFF_OFF);
    int*   rank   = (int*)(ws + RANK_OFF);

    // zero deg; harness poisons ws with 0xAA
    hipMemsetAsync(ws + DEG_OFF, 0, N_NODES * sizeof(int), stream);

    k_count<<<(N_EDGES + 255) / 256, 256, 0, stream>>>(ei, deg, rank, Wl, Wr, bl, br, Wt, blr);
    k_scan1<<<NB_SCAN, 256, 0, stream>>>(deg, scan, bsums);
    k_scan2<<<1, 256, 0, stream>>>(bsums, boffs);
    k_fix<<<NB_SCAN, 256, 0, stream>>>(deg, scan, boffs);

    k_scatgemm<<<SCAT_BLOCKS + GEMM_BLOCKS, 384, 0, stream>>>(ei, ew, deg, rank, pair,
                                                              x, Wt, blr, xl, xr);

    k_node<<<N_NODES / NPB, 192, 0, stream>>>(x, bias, att, We, scan, boffs,
                                              pair, xl, xr, out);
}

// Round 12
// 253.468 us; speedup vs baseline: 1.3383x; 1.0118x over previous
//
#include <hip/hip_runtime.h>
#include <hip/hip_bf16.h>
#include <math.h>

#define N_NODES 50000
#define N_EDGES 400000
#define HEADS 6
#define DIMS 32
#define FEAT 192
#define NEG_SLOPE 0.2f

typedef __attribute__((ext_vector_type(8))) short short8;
typedef __attribute__((ext_vector_type(4))) float f32x4;

__device__ __forceinline__ unsigned short f2bu(float f) {
    __hip_bfloat16 h = __float2bfloat16(f);
    unsigned short u; __builtin_memcpy(&u, &h, 2); return u;
}
__device__ __forceinline__ float bu2f(unsigned short u) {
    return __uint_as_float(((unsigned)u) << 16);
}

// ---------------- workspace layout (byte offsets) ----------------
#define XL_OFF    0            // ushort N*192 = 19,200,000
#define XR_OFF    19200000     // ushort N*192
#define WT_OFF    38400000     // short 384*192 = 147,456
#define BLR_OFF   38547456     // float 384
#define PAIR_OFF  38548992     // int2 E = 3,200,000
#define DEG_OFF   41748992     // int N (counts -> exclusive starts via k_fix)
#define SCAN_OFF  42148992     // int N
#define BSUM_OFF  42348992     // int 256
#define BOFF_OFF  42350016     // int 256
#define RANK_OFF  42351040     // int E = 1,600,000 (per-edge rank within dst)
#define NB_SCAN ((N_NODES + 255) / 256)   // 196

// ---------------- count (1 atomic/edge, rank persisted) + weight pack ----------------
__global__ __launch_bounds__(256) void k_count(const int* __restrict__ ei,
                                               int* __restrict__ deg,
                                               int* __restrict__ rank,
                                               const float* __restrict__ Wl,
                                               const float* __restrict__ Wr,
                                               const float* __restrict__ bl,
                                               const float* __restrict__ br,
                                               short* __restrict__ Wt,
                                               float* __restrict__ blr) {
    int e = blockIdx.x * blockDim.x + threadIdx.x;
    if (e < N_EDGES) rank[e] = atomicAdd(&deg[ei[N_EDGES + e]], 1);
    if (e < 384 * FEAT) {   // pack Wt[n][k] = W[k][n] (bf16)
        int n = e / FEAT, k = e - n * FEAT;
        float v = (n < FEAT) ? Wl[k * FEAT + n] : Wr[k * FEAT + (n - FEAT)];
        Wt[n * FEAT + k] = (short)f2bu(v);
    }
    if (e < 384) blr[e] = (e < FEAT) ? bl[e] : br[e - FEAT];
}

__global__ __launch_bounds__(256) void k_scan1(const int* __restrict__ deg,
                                               int* __restrict__ scan,
                                               int* __restrict__ bsums) {
    int t = threadIdx.x;
    int i = blockIdx.x * 256 + t;
    int v = (i < N_NODES) ? deg[i] : 0;
    __shared__ int s[256];
    s[t] = v; __syncthreads();
    for (int off = 1; off < 256; off <<= 1) {
        int u = (t >= off) ? s[t - off] : 0;
        __syncthreads();
        s[t] += u;
        __syncthreads();
    }
    if (i < N_NODES) scan[i] = s[t];   // inclusive within block
    if (t == 255) bsums[blockIdx.x] = s[255];
}

__global__ __launch_bounds__(256) void k_scan2(int* __restrict__ bsums,
                                               int* __restrict__ boffs) {
    int t = threadIdx.x;
    int v = (t < NB_SCAN) ? bsums[t] : 0;
    __shared__ int s[256];
    s[t] = v; __syncthreads();
    for (int off = 1; off < 256; off <<= 1) {
        int u = (t >= off) ? s[t - off] : 0;
        __syncthreads();
        s[t] += u;
        __syncthreads();
    }
    boffs[t] = s[t] - v;   // exclusive block offsets
}

// deg[d]: count -> EXCLUSIVE start (one coalesced pass). Scatter then needs
// zero atomics: slot = deg[d] + rank[e] (random READ instead of random atomic).
__global__ __launch_bounds__(256) void k_fix(int* __restrict__ deg,
                                             const int* __restrict__ scan,
                                             const int* __restrict__ boffs) {
    int i = blockIdx.x * 256 + threadIdx.x;
    if (i < N_NODES) deg[i] = boffs[i >> 8] + scan[i] - deg[i];
}

// ---------------- fused scatter + MFMA GEMM (block-range split) ----------------
#define SCAT_BLOCKS ((N_EDGES + 383) / 384)   // 1042
#define GEMM_BLOCKS ((N_NODES + 63) / 64)     // 782 (last block: 16-row tail)
#define OSTRIDE 392
#define ASTRIDE 200
__global__ __launch_bounds__(384) void k_scatgemm(const int* __restrict__ ei,
                                                  const float* __restrict__ ew,
                                                  const int* __restrict__ deg,
                                                  const int* __restrict__ rank,
                                                  int2* __restrict__ pair,
                                                  const float* __restrict__ x,
                                                  const short* __restrict__ Wt,
                                                  const float* __restrict__ blr,
                                                  unsigned short* __restrict__ xl,
                                                  unsigned short* __restrict__ xr) {
    __shared__ unsigned short sOut[16 * OSTRIDE];
    __shared__ unsigned short sA[64 * ASTRIDE];
    if (blockIdx.x < SCAT_BLOCKS) {
        int e = blockIdx.x * 384 + threadIdx.x;
        if (e < N_EDGES) {
            int d = ei[N_EDGES + e];
            int slot = deg[d] + rank[e];         // atomic-free scatter
            int2 p; p.x = ei[e]; p.y = __float_as_int(ew[e]);
            pair[slot] = p;
        }
        return;
    }
    size_t row0 = (size_t)(blockIdx.x - SCAT_BLOCKS) * 64;

    // ---- stage A tile: 64 rows x 192 floats -> bf16 in LDS (4 segs/thread)
#pragma unroll
    for (int s = 0; s < 4; s++) {
        int q = threadIdx.x + s * 384;
        int row = q / 24, k0 = (q - row * 24) * 8;
        size_t gr = row0 + row;
        const float* ap = x + (gr < N_NODES ? gr : row0) * FEAT + k0;  // safe dummy
        float4 v0 = *(const float4*)ap;
        float4 v1 = *(const float4*)(ap + 4);
        unsigned short tmp[8];
        tmp[0] = f2bu(v0.x); tmp[1] = f2bu(v0.y); tmp[2] = f2bu(v0.z); tmp[3] = f2bu(v0.w);
        tmp[4] = f2bu(v1.x); tmp[5] = f2bu(v1.y); tmp[6] = f2bu(v1.z); tmp[7] = f2bu(v1.w);
        int kw = (k0 >> 1) ^ ((row & 7) << 2);
        *(uint4*)&sA[row * ASTRIDE + kw * 2] = *(const uint4*)tmp;
    }
    __syncthreads();

    int wv   = threadIdx.x >> 6;
    int lane = threadIdx.x & 63;
    int m    = lane & 15;
    int kg   = lane >> 4;
    int ncol0 = wv * 64;

    f32x4 acc[4][4];   // [row-subtile][col-subtile]
#pragma unroll
    for (int r = 0; r < 4; r++)
#pragma unroll
        for (int j = 0; j < 4; j++) acc[r][j] = (f32x4){0.f, 0.f, 0.f, 0.f};

#pragma unroll
    for (int ks = 0; ks < 6; ks++) {
        int kb = ks * 32 + kg * 8;
        int kw = (kb >> 1) ^ ((m & 7) << 2);     // (m+16k)&7 == m&7: same swizzle
        short8 af0 = *(const short8*)&sA[m * ASTRIDE + kw * 2];
        short8 af1 = *(const short8*)&sA[(16 + m) * ASTRIDE + kw * 2];
        short8 af2 = *(const short8*)&sA[(32 + m) * ASTRIDE + kw * 2];
        short8 af3 = *(const short8*)&sA[(48 + m) * ASTRIDE + kw * 2];
        const short* wp = Wt + (size_t)(ncol0 + m) * FEAT + kb;
#pragma unroll
        for (int j = 0; j < 4; j++) {            // one B tile live at a time
            short8 b = *(const short8*)(wp + j * 16 * FEAT);
            acc[0][j] = __builtin_amdgcn_mfma_f32_16x16x32_bf16(af0, b, acc[0][j], 0, 0, 0);
            acc[1][j] = __builtin_amdgcn_mfma_f32_16x16x32_bf16(af1, b, acc[1][j], 0, 0, 0);
            acc[2][j] = __builtin_amdgcn_mfma_f32_16x16x32_bf16(af2, b, acc[2][j], 0, 0, 0);
            acc[3][j] = __builtin_amdgcn_mfma_f32_16x16x32_bf16(af3, b, acc[3][j], 0, 0, 0);
        }
    }

    // ---- epilogue: four 16-row passes through sOut
#pragma unroll
    for (int pass = 0; pass < 4; pass++) {
        if (pass) __syncthreads();   // prev pass copy done before overwrite
#pragma unroll
        for (int t4 = 0; t4 < 4; t4++) {
            int cc = ncol0 + t4 * 16 + m;
            float bv = blr[cc];
#pragma unroll
            for (int r = 0; r < 4; r++) {
                sOut[(kg * 4 + r) * OSTRIDE + cc] = f2bu(acc[pass][t4][r] + bv);
            }
        }
        __syncthreads();
        for (int q = threadIdx.x; q < 768; q += 384) {
            int row = q / 48, p = q - row * 48;
            size_t gr = row0 + pass * 16 + row;
            if (gr < N_NODES) {
                uint4 v = *(const uint4*)&sOut[row * OSTRIDE + p * 8];
                if (p < 24) *(uint4*)(xl + gr * FEAT + p * 8) = v;
                else        *(uint4*)(xr + gr * FEAT + (p - 24) * 8) = v;
            }
        }
    }
}

// ---------------- fused node kernel: WAVE-AUTONOMOUS ----------------
// 1 wave (64 thr) per block, NPB=2 nodes, CE=8 edge-chunks; 25000 blocks.
// Every wave is an independent serial chain (barriers are intra-wave = free).
// Per-edge issued work identical to the 192-thr version (3 channels/lane);
// only the concurrency structure changes — discriminates chain-limited vs
// random-access-floor hypotheses for k_node's ~102us.
#define NPB 2
#define CE 8
#define RS 100   // uints per row; rows 16B aligned
#define APAD 36  // att/We row stride (float4-aligned)
__global__ __launch_bounds__(64) void k_node(const float* __restrict__ x,
                                             const float* __restrict__ bias,
                                             const float* __restrict__ att,
                                             const float* __restrict__ We,
                                             const int* __restrict__ scan,
                                             const int* __restrict__ boffs,
                                             const int2* __restrict__ pair,
                                             const unsigned short* __restrict__ xl,
                                             const unsigned short* __restrict__ xr,
                                             float* __restrict__ out) {
    __shared__ __align__(16) unsigned int sXL[CE * RS];
    __shared__ __align__(16) unsigned int sXR[NPB * RS];
    __shared__ float sEx[CE * HEADS];
    __shared__ float sExS[NPB * HEADS];
    __shared__ int   sSrc[2][CE];
    __shared__ float sW[2][CE];
    __shared__ int   sDst[2][CE];
    __shared__ int   sStart[NPB + 1];
    __shared__ __align__(16) float sAttP[HEADS * APAD];
    __shared__ __align__(16) float sWeP[HEADS * APAD];
    __shared__ float sDen[NPB * HEADS];
    __shared__ float sWsm[NPB];

    int t = threadIdx.x;            // 0..63
    int n0 = blockIdx.x * NPB;

    int gbase = boffs[n0 >> 8] + ((n0 & 255) ? scan[n0 - 1] : 0);
    int n2 = n0 + NPB;
    int gend = (n2 >= N_NODES) ? N_EDGES
             : (boffs[n2 >> 8] + ((n2 & 255) ? scan[n2 - 1] : 0));
    int etot = gend - gbase;
    int c0 = min(etot, CE);

    if (t < c0) { int2 p = pair[gbase + t]; sSrc[0][t] = p.x; sW[0][t] = __int_as_float(p.y); }

    for (int q = t; q < HEADS * APAD; q += 64) {
        int hh = q / APAD, c = q - hh * APAD;
        if (c < 32) { sAttP[q] = att[hh * 32 + c]; sWeP[q] = We[hh * 32 + c]; }
    }
    if (t <= NPB) {
        int n = n0 + t;
        int st;
        if (n >= N_NODES) st = N_EDGES;
        else {
            int b = n >> 8;
            st = boffs[b] + ((n & 255) ? scan[n - 1] : 0);
        }
        sStart[t] = st;
    }
    if (t < NPB) {   // sDst[0] pre-fill with self-computed bounds (no sStart dep)
        int n = n0 + t;
        int a = boffs[n >> 8] + ((n & 255) ? scan[n - 1] : 0);
        int n1 = n + 1;
        int b = (n1 >= N_NODES) ? N_EDGES
              : (boffs[n1 >> 8] + ((n1 & 255) ? scan[n1 - 1] : 0));
        int lo = a - gbase; if (lo < 0) lo = 0;
        int hi = b - gbase; if (hi > c0) hi = c0;
        for (int q = lo; q < hi; q++) sDst[0][q] = t;
    }
    if (t < NPB * 24) {   // stage 2 xr rows: 48 uint4
        int nn = t / 24, p = t - nn * 24;
        *(uint4*)&sXR[nn * RS + p * 4] = ((const uint4*)(xr + (size_t)(n0 + nn) * FEAT))[p];
    }
    __syncthreads();

    float acc[NPB][3];
#pragma unroll
    for (int nn = 0; nn < NPB; nn++) { acc[nn][0] = 0.f; acc[nn][1] = 0.f; acc[nn][2] = 0.f; }
    float redR = 0.f;                               // den (t<12) OR wsm (t in [12,14))
    int nnD = t / HEADS, hhD = t - nnD * HEADS;     // den ownership (t < 12)

    int nch = (etot + CE - 1) / CE;
    for (int ci = 0; ci < nch; ci++) {
        int i0 = ci * CE;
        int c  = min(etot - i0, CE);
        int cn = min(etot - i0 - CE, CE);   // next chunk size
        int cb = ci & 1, nb = cb ^ 1;

        // A: gather xl chunk ci -> sXL (c*24 <= 192 uint4, 3 iters); prefetch pair ci+1
        {
            int nld = c * 24;
#pragma unroll
            for (int s = 0; s < 3; s++) {
                int q = t + s * 64;
                if (q < nld) {
                    int i = q / 24, p = q - i * 24;
                    *(uint4*)&sXL[i * RS + p * 4] =
                        *(const uint4*)(xl + (size_t)sSrc[cb][i] * FEAT + p * 8);
                }
            }
        }
        int2 P;
        if (t < cn) P = pair[gbase + i0 + CE + t];
        if (t < NPB && cn > 0) {
            int lo = sStart[t] - gbase - i0 - CE;     if (lo < 0) lo = 0;
            int hi = sStart[t + 1] - gbase - i0 - CE; if (hi > cn) hi = cn;
            for (int q = lo; q < hi; q++) sDst[nb][q] = t;
        }
        __syncthreads();

        // C: alpha + exp (thread per (edge, head), t < c*6 <= 48)
        if (t < c * HEADS) {
            int i = t / HEADS, hh = t - i * HEADS;
            int nn = sDst[cb][i];
            float w = sW[cb][i];
            const uint4* pa = (const uint4*)&sXL[i * RS + hh * 16];
            const uint4* pb = (const uint4*)&sXR[nn * RS + hh * 16];
            float alpha0 = 0.f, alpha1 = 0.f;
#pragma unroll
            for (int g = 0; g < 4; g++) {
                uint4 a4 = pa[g];
                uint4 b4 = pb[g];
                float4 we0 = *(const float4*)&sWeP[hh * APAD + g * 8];
                float4 we1 = *(const float4*)&sWeP[hh * APAD + g * 8 + 4];
                float4 at0 = *(const float4*)&sAttP[hh * APAD + g * 8];
                float4 at1 = *(const float4*)&sAttP[hh * APAD + g * 8 + 4];
                float wec[8] = {we0.x, we0.y, we0.z, we0.w, we1.x, we1.y, we1.z, we1.w};
                float atc[8] = {at0.x, at0.y, at0.z, at0.w, at1.x, at1.y, at1.z, at1.w};
                unsigned aw[4] = {a4.x, a4.y, a4.z, a4.w};
                unsigned bw[4] = {b4.x, b4.y, b4.z, b4.w};
#pragma unroll
                for (int q = 0; q < 4; q++) {
                    float m0 = bu2f((unsigned short)aw[q]) + bu2f((unsigned short)bw[q]) + w * wec[q * 2];
                    m0 = fmaxf(m0, NEG_SLOPE * m0);
                    alpha0 += m0 * atc[q * 2];
                    float m1 = bu2f((unsigned short)(aw[q] >> 16)) + bu2f((unsigned short)(bw[q] >> 16)) + w * wec[q * 2 + 1];
                    m1 = fmaxf(m1, NEG_SLOPE * m1);
                    alpha1 += m1 * atc[q * 2 + 1];
                }
            }
            sEx[t] = __expf(alpha0 + alpha1);
        }
        if (t < cn) { sSrc[nb][t] = P.x; sW[nb][t] = __int_as_float(P.y); }
        __syncthreads();

        // E: accumulate — each lane owns channels {t, t+64, t+128} (heads hb, 2+hb, 4+hb)
        {
            int cwb = t >> 1;       // base word in row
            int hb  = t >> 5;       // 0/1
#pragma unroll
            for (int nn = 0; nn < NPB; nn++) {
                int lo = sStart[nn] - gbase - i0;     if (lo < 0) lo = 0;
                int hi = sStart[nn + 1] - gbase - i0; if (hi > c) hi = c;
                for (int i = lo; i < hi; i++) {
                    const unsigned int* row = &sXL[i * RS];
                    float e0 = sEx[i * HEADS + hb];
                    float e1 = sEx[i * HEADS + 2 + hb];
                    float e2 = sEx[i * HEADS + 4 + hb];
                    unsigned u0 = row[cwb], u1 = row[cwb + 32], u2 = row[cwb + 64];
                    unsigned short v0 = (t & 1) ? (unsigned short)(u0 >> 16) : (unsigned short)u0;
                    unsigned short v1 = (t & 1) ? (unsigned short)(u1 >> 16) : (unsigned short)u1;
                    unsigned short v2 = (t & 1) ? (unsigned short)(u2 >> 16) : (unsigned short)u2;
                    acc[nn][0] += e0 * bu2f(v0);
                    acc[nn][1] += e1 * bu2f(v1);
                    acc[nn][2] += e2 * bu2f(v2);
                }
            }
            if (t < NPB * HEADS) {          // den: 12 lanes
                int lo = sStart[nnD] - gbase - i0;     if (lo < 0) lo = 0;
                int hi = sStart[nnD + 1] - gbase - i0; if (hi > c) hi = c;
                for (int i = lo; i < hi; i++) redR += sEx[i * HEADS + hhD];
            } else if (t < NPB * HEADS + NPB) {   // wsm: 2 lanes
                int nw = t - NPB * HEADS;
                int lo = sStart[nw] - gbase - i0;     if (lo < 0) lo = 0;
                int hi = sStart[nw + 1] - gbase - i0; if (hi > c) hi = c;
                for (int i = lo; i < hi; i++) redR += sW[cb][i];
            }
        }
        __syncthreads();   // protects sXL/sDst overwrite next iter
    }

    if (t < NPB * HEADS) sDen[t] = redR;
    else if (t < NPB * HEADS + NPB) sWsm[t - NPB * HEADS] = redR;
    __syncthreads();

    // self-loop alpha (12 lanes, one per (nn,hh)); self xl row from GLOBAL
    if (t < NPB * HEADS) {
        int nn = nnD, hh = hhD;
        int dg = sStart[nn + 1] - sStart[nn];
        float w = sWsm[nn] / fmaxf((float)dg, 1.0f);
        const uint4* pa = (const uint4*)(xl + (size_t)(n0 + nn) * FEAT + hh * 32);
        const uint4* pb = (const uint4*)&sXR[nn * RS + hh * 16];
        float alpha0 = 0.f, alpha1 = 0.f;
#pragma unroll
        for (int g = 0; g < 4; g++) {
            uint4 a4 = pa[g];
            uint4 b4 = pb[g];
            float4 we0 = *(const float4*)&sWeP[hh * APAD + g * 8];
            float4 we1 = *(const float4*)&sWeP[hh * APAD + g * 8 + 4];
            float4 at0 = *(const float4*)&sAttP[hh * APAD + g * 8];
            float4 at1 = *(const float4*)&sAttP[hh * APAD + g * 8 + 4];
            float wec[8] = {we0.x, we0.y, we0.z, we0.w, we1.x, we1.y, we1.z, we1.w};
            float atc[8] = {at0.x, at0.y, at0.z, at0.w, at1.x, at1.y, at1.z, at1.w};
            unsigned aw[4] = {a4.x, a4.y, a4.z, a4.w};
            unsigned bw[4] = {b4.x, b4.y, b4.z, b4.w};
#pragma unroll
            for (int q = 0; q < 4; q++) {
                float m0 = bu2f((unsigned short)aw[q]) + bu2f((unsigned short)bw[q]) + w * wec[q * 2];
                m0 = fmaxf(m0, NEG_SLOPE * m0);
                alpha0 += m0 * atc[q * 2];
                float m1 = bu2f((unsigned short)(aw[q] >> 16)) + bu2f((unsigned short)(bw[q] >> 16)) + w * wec[q * 2 + 1];
                m1 = fmaxf(m1, NEG_SLOPE * m1);
                alpha1 += m1 * atc[q * 2 + 1];
            }
        }
        sExS[t] = __expf(alpha0 + alpha1);
    }
    __syncthreads();

    // epilogue: 3 channels/lane x 2 nodes; self-loop add, divide, residual+bias+relu
#pragma unroll
    for (int s = 0; s < 3; s++) {
        int ch = t + s * 64;
        float bj = bias[ch];
        int hh = ch >> 5;
#pragma unroll
        for (int nn = 0; nn < NPB; nn++) {
            float exS = sExS[nn * HEADS + hh];
            size_t off = (size_t)(n0 + nn) * FEAT + ch;
            float xsv = bu2f(xl[off]);
            float num = acc[nn][s] + exS * xsv;
            float dn  = sDen[nn * HEADS + hh] + exS;
            float val = x[off] + bj + num / dn;
            out[off] = (val > 0.f) ? val : 0.f;
        }
    }
}

extern "C" void kernel_launch(void* const* d_in, const int* in_sizes, int n_in,
                              void* d_out, int out_size, void* d_ws, size_t ws_size,
                              hipStream_t stream) {
    const float* x    = (const float*)d_in[0];
    const int*   ei   = (const int*)d_in[1];
    const float* ew   = (const float*)d_in[2];
    const float* Wl   = (const float*)d_in[3];
    const float* bl   = (const float*)d_in[4];
    const float* Wr   = (const float*)d_in[5];
    const float* br   = (const float*)d_in[6];
    const float* We   = (const float*)d_in[7];
    const float* att  = (const float*)d_in[8];
    const float* bias = (const float*)d_in[9];
    float* out = (float*)d_out;

    char* ws = (char*)d_ws;
    unsigned short* xl = (unsigned short*)(ws + XL_OFF);
    unsigned short* xr = (unsigned short*)(ws + XR_OFF);
    short* Wt     = (short*)(ws + WT_OFF);
    float* blr    = (float*)(ws + BLR_OFF);
    int2*  pair   = (int2*)(ws + PAIR_OFF);
    int*   deg    = (int*)(ws + DEG_OFF);
    int*   scan   = (int*)(ws + SCAN_OFF);
    int*   bsums  = (int*)(ws + BSUM_OFF);
    int*   boffs  = (int*)(ws + BOFF_OFF);
    int*   rank   = (int*)(ws + RANK_OFF);

    // zero deg; harness poisons ws with 0xAA
    hipMemsetAsync(ws + DEG_OFF, 0, N_NODES * sizeof(int), stream);

    k_count<<<(N_EDGES + 255) / 256, 256, 0, stream>>>(ei, deg, rank, Wl, Wr, bl, br, Wt, blr);
    k_scan1<<<NB_SCAN, 256, 0, stream>>>(deg, scan, bsums);
    k_scan2<<<1, 256, 0, stream>>>(bsums, boffs);
    k_fix<<<NB_SCAN, 256, 0, stream>>>(deg, scan, boffs);

    k_scatgemm<<<SCAT_BLOCKS + GEMM_BLOCKS, 384, 0, stream>>>(ei, ew, deg, rank, pair,
                                                              x, Wt, blr, xl, xr);

    k_node<<<N_NODES / NPB, 64, 0, stream>>>(x, bias, att, We, scan, boffs,
                                             pair, xl, xr, out);
}

// Round 13
// 252.490 us; speedup vs baseline: 1.3435x; 1.0039x over previous
//
#include <hip/hip_runtime.h>
#include <hip/hip_bf16.h>
#include <math.h>

#define N_NODES 50000
#define N_EDGES 400000
#define HEADS 6
#define DIMS 32
#define FEAT 192
#define NEG_SLOPE 0.2f

typedef __attribute__((ext_vector_type(8))) short short8;
typedef __attribute__((ext_vector_type(4))) float f32x4;

__device__ __forceinline__ unsigned short f2bu(float f) {
    __hip_bfloat16 h = __float2bfloat16(f);
    unsigned short u; __builtin_memcpy(&u, &h, 2); return u;
}
__device__ __forceinline__ float bu2f(unsigned short u) {
    return __uint_as_float(((unsigned)u) << 16);
}

// ---------------- workspace layout (byte offsets) ----------------
#define XL_OFF    0            // ushort N*192 = 19,200,000
#define XR_OFF    19200000     // ushort N*192
#define WT_OFF    38400000     // short 384*192 = 147,456
#define BLR_OFF   38547456     // float 384
#define PAIR_OFF  38548992     // int2 E = 3,200,000
#define DEG_OFF   41748992     // int N (counts -> exclusive starts via k_fix)
#define SCAN_OFF  42148992     // int N
#define BSUM_OFF  42348992     // int 256
#define BOFF_OFF  42350016     // int 256
#define RANK_OFF  42351040     // int E = 1,600,000 (per-edge rank within dst)
#define NB_SCAN ((N_NODES + 255) / 256)   // 196

// ---------------- pack weights + zero deg (replaces memset launch) ----------------
__global__ __launch_bounds__(256) void k_pack(const float* __restrict__ Wl,
                                              const float* __restrict__ Wr,
                                              const float* __restrict__ bl,
                                              const float* __restrict__ br,
                                              short* __restrict__ Wt,
                                              float* __restrict__ blr,
                                              int* __restrict__ deg) {
    int e = blockIdx.x * 256 + threadIdx.x;   // 288 blocks -> 73728 threads
    if (e < 384 * FEAT) {   // pack Wt[n][k] = W[k][n] (bf16)
        int n = e / FEAT, k = e - n * FEAT;
        float v = (n < FEAT) ? Wl[k * FEAT + n] : Wr[k * FEAT + (n - FEAT)];
        Wt[n * FEAT + k] = (short)f2bu(v);
    }
    if (e < 384) blr[e] = (e < FEAT) ? bl[e] : br[e - FEAT];
    if (e < N_NODES) deg[e] = 0;
}

// ---------------- fused count + MFMA GEMM (independent work, one launch) --------
// Count blocks (400K random atomics) and GEMM blocks (MFMA-dense) overlap on
// the device instead of running serially.
#define CNT_BLOCKS ((N_EDGES + 383) / 384)    // 1042
#define GEMM_BLOCKS ((N_NODES + 63) / 64)     // 782 (last block: 16-row tail)
#define OSTRIDE 392
#define ASTRIDE 200
__global__ __launch_bounds__(384) void k_countgemm(const int* __restrict__ ei,
                                                   int* __restrict__ deg,
                                                   int* __restrict__ rank,
                                                   const float* __restrict__ x,
                                                   const short* __restrict__ Wt,
                                                   const float* __restrict__ blr,
                                                   unsigned short* __restrict__ xl,
                                                   unsigned short* __restrict__ xr) {
    __shared__ unsigned short sOut[16 * OSTRIDE];
    __shared__ unsigned short sA[64 * ASTRIDE];
    if (blockIdx.x < CNT_BLOCKS) {
        int e = blockIdx.x * 384 + threadIdx.x;
        if (e < N_EDGES) rank[e] = atomicAdd(&deg[ei[N_EDGES + e]], 1);
        return;
    }
    size_t row0 = (size_t)(blockIdx.x - CNT_BLOCKS) * 64;

    // ---- stage A tile: 64 rows x 192 floats -> bf16 in LDS (4 segs/thread)
#pragma unroll
    for (int s = 0; s < 4; s++) {
        int q = threadIdx.x + s * 384;
        int row = q / 24, k0 = (q - row * 24) * 8;
        size_t gr = row0 + row;
        const float* ap = x + (gr < N_NODES ? gr : row0) * FEAT + k0;  // safe dummy
        float4 v0 = *(const float4*)ap;
        float4 v1 = *(const float4*)(ap + 4);
        unsigned short tmp[8];
        tmp[0] = f2bu(v0.x); tmp[1] = f2bu(v0.y); tmp[2] = f2bu(v0.z); tmp[3] = f2bu(v0.w);
        tmp[4] = f2bu(v1.x); tmp[5] = f2bu(v1.y); tmp[6] = f2bu(v1.z); tmp[7] = f2bu(v1.w);
        int kw = (k0 >> 1) ^ ((row & 7) << 2);
        *(uint4*)&sA[row * ASTRIDE + kw * 2] = *(const uint4*)tmp;
    }
    __syncthreads();

    int wv   = threadIdx.x >> 6;
    int lane = threadIdx.x & 63;
    int m    = lane & 15;
    int kg   = lane >> 4;
    int ncol0 = wv * 64;

    f32x4 acc[4][4];   // [row-subtile][col-subtile]
#pragma unroll
    for (int r = 0; r < 4; r++)
#pragma unroll
        for (int j = 0; j < 4; j++) acc[r][j] = (f32x4){0.f, 0.f, 0.f, 0.f};

#pragma unroll
    for (int ks = 0; ks < 6; ks++) {
        int kb = ks * 32 + kg * 8;
        int kw = (kb >> 1) ^ ((m & 7) << 2);     // (m+16k)&7 == m&7: same swizzle
        short8 af0 = *(const short8*)&sA[m * ASTRIDE + kw * 2];
        short8 af1 = *(const short8*)&sA[(16 + m) * ASTRIDE + kw * 2];
        short8 af2 = *(const short8*)&sA[(32 + m) * ASTRIDE + kw * 2];
        short8 af3 = *(const short8*)&sA[(48 + m) * ASTRIDE + kw * 2];
        const short* wp = Wt + (size_t)(ncol0 + m) * FEAT + kb;
#pragma unroll
        for (int j = 0; j < 4; j++) {            // one B tile live at a time
            short8 b = *(const short8*)(wp + j * 16 * FEAT);
            acc[0][j] = __builtin_amdgcn_mfma_f32_16x16x32_bf16(af0, b, acc[0][j], 0, 0, 0);
            acc[1][j] = __builtin_amdgcn_mfma_f32_16x16x32_bf16(af1, b, acc[1][j], 0, 0, 0);
            acc[2][j] = __builtin_amdgcn_mfma_f32_16x16x32_bf16(af2, b, acc[2][j], 0, 0, 0);
            acc[3][j] = __builtin_amdgcn_mfma_f32_16x16x32_bf16(af3, b, acc[3][j], 0, 0, 0);
        }
    }

    // ---- epilogue: four 16-row passes through sOut
#pragma unroll
    for (int pass = 0; pass < 4; pass++) {
        if (pass) __syncthreads();   // prev pass copy done before overwrite
#pragma unroll
        for (int t4 = 0; t4 < 4; t4++) {
            int cc = ncol0 + t4 * 16 + m;
            float bv = blr[cc];
#pragma unroll
            for (int r = 0; r < 4; r++) {
                sOut[(kg * 4 + r) * OSTRIDE + cc] = f2bu(acc[pass][t4][r] + bv);
            }
        }
        __syncthreads();
        for (int q = threadIdx.x; q < 768; q += 384) {
            int row = q / 48, p = q - row * 48;
            size_t gr = row0 + pass * 16 + row;
            if (gr < N_NODES) {
                uint4 v = *(const uint4*)&sOut[row * OSTRIDE + p * 8];
                if (p < 24) *(uint4*)(xl + gr * FEAT + p * 8) = v;
                else        *(uint4*)(xr + gr * FEAT + (p - 24) * 8) = v;
            }
        }
    }
}

__global__ __launch_bounds__(256) void k_scan1(const int* __restrict__ deg,
                                               int* __restrict__ scan,
                                               int* __restrict__ bsums) {
    int t = threadIdx.x;
    int i = blockIdx.x * 256 + t;
    int v = (i < N_NODES) ? deg[i] : 0;
    __shared__ int s[256];
    s[t] = v; __syncthreads();
    for (int off = 1; off < 256; off <<= 1) {
        int u = (t >= off) ? s[t - off] : 0;
        __syncthreads();
        s[t] += u;
        __syncthreads();
    }
    if (i < N_NODES) scan[i] = s[t];   // inclusive within block
    if (t == 255) bsums[blockIdx.x] = s[255];
}

__global__ __launch_bounds__(256) void k_scan2(int* __restrict__ bsums,
                                               int* __restrict__ boffs) {
    int t = threadIdx.x;
    int v = (t < NB_SCAN) ? bsums[t] : 0;
    __shared__ int s[256];
    s[t] = v; __syncthreads();
    for (int off = 1; off < 256; off <<= 1) {
        int u = (t >= off) ? s[t - off] : 0;
        __syncthreads();
        s[t] += u;
        __syncthreads();
    }
    boffs[t] = s[t] - v;   // exclusive block offsets
}

// deg[d]: count -> EXCLUSIVE start (one coalesced pass)
__global__ __launch_bounds__(256) void k_fix(int* __restrict__ deg,
                                             const int* __restrict__ scan,
                                             const int* __restrict__ boffs) {
    int i = blockIdx.x * 256 + threadIdx.x;
    if (i < N_NODES) deg[i] = boffs[i >> 8] + scan[i] - deg[i];
}

// ---------------- atomic-free scatter (standalone; after fix) ----------------
__global__ __launch_bounds__(256) void k_scatter(const int* __restrict__ ei,
                                                 const float* __restrict__ ew,
                                                 const int* __restrict__ deg,
                                                 const int* __restrict__ rank,
                                                 int2* __restrict__ pair) {
    int e = blockIdx.x * 256 + threadIdx.x;
    if (e < N_EDGES) {
        int d = ei[N_EDGES + e];
        int slot = deg[d] + rank[e];
        int2 p; p.x = ei[e]; p.y = __float_as_int(ew[e]);
        pair[slot] = p;
    }
}

// ---------------- fused node kernel: WAVE-AUTONOMOUS (closed at ~100us) --------
// 1 wave (64 thr) per block, NPB=2 nodes, CE=8 edge-chunks; 25000 blocks.
// r12 measurement: VALUBusy 60% with duration pinned vs r11's 39% -> k_node is
// bounded by the random xl-gather stream (L2/L3 random-access floor), closed.
#define NPB 2
#define CE 8
#define RS 100   // uints per row; rows 16B aligned
#define APAD 36  // att/We row stride (float4-aligned)
__global__ __launch_bounds__(64) void k_node(const float* __restrict__ x,
                                             const float* __restrict__ bias,
                                             const float* __restrict__ att,
                                             const float* __restrict__ We,
                                             const int* __restrict__ scan,
                                             const int* __restrict__ boffs,
                                             const int2* __restrict__ pair,
                                             const unsigned short* __restrict__ xl,
                                             const unsigned short* __restrict__ xr,
                                             float* __restrict__ out) {
    __shared__ __align__(16) unsigned int sXL[CE * RS];
    __shared__ __align__(16) unsigned int sXR[NPB * RS];
    __shared__ float sEx[CE * HEADS];
    __shared__ float sExS[NPB * HEADS];
    __shared__ int   sSrc[2][CE];
    __shared__ float sW[2][CE];
    __shared__ int   sDst[2][CE];
    __shared__ int   sStart[NPB + 1];
    __shared__ __align__(16) float sAttP[HEADS * APAD];
    __shared__ __align__(16) float sWeP[HEADS * APAD];
    __shared__ float sDen[NPB * HEADS];
    __shared__ float sWsm[NPB];

    int t = threadIdx.x;            // 0..63
    int n0 = blockIdx.x * NPB;

    int gbase = boffs[n0 >> 8] + ((n0 & 255) ? scan[n0 - 1] : 0);
    int n2 = n0 + NPB;
    int gend = (n2 >= N_NODES) ? N_EDGES
             : (boffs[n2 >> 8] + ((n2 & 255) ? scan[n2 - 1] : 0));
    int etot = gend - gbase;
    int c0 = min(etot, CE);

    if (t < c0) { int2 p = pair[gbase + t]; sSrc[0][t] = p.x; sW[0][t] = __int_as_float(p.y); }

    for (int q = t; q < HEADS * APAD; q += 64) {
        int hh = q / APAD, c = q - hh * APAD;
        if (c < 32) { sAttP[q] = att[hh * 32 + c]; sWeP[q] = We[hh * 32 + c]; }
    }
    if (t <= NPB) {
        int n = n0 + t;
        int st;
        if (n >= N_NODES) st = N_EDGES;
        else {
            int b = n >> 8;
            st = boffs[b] + ((n & 255) ? scan[n - 1] : 0);
        }
        sStart[t] = st;
    }
    if (t < NPB) {   // sDst[0] pre-fill with self-computed bounds (no sStart dep)
        int n = n0 + t;
        int a = boffs[n >> 8] + ((n & 255) ? scan[n - 1] : 0);
        int n1 = n + 1;
        int b = (n1 >= N_NODES) ? N_EDGES
              : (boffs[n1 >> 8] + ((n1 & 255) ? scan[n1 - 1] : 0));
        int lo = a - gbase; if (lo < 0) lo = 0;
        int hi = b - gbase; if (hi > c0) hi = c0;
        for (int q = lo; q < hi; q++) sDst[0][q] = t;
    }
    if (t < NPB * 24) {   // stage 2 xr rows: 48 uint4
        int nn = t / 24, p = t - nn * 24;
        *(uint4*)&sXR[nn * RS + p * 4] = ((const uint4*)(xr + (size_t)(n0 + nn) * FEAT))[p];
    }
    __syncthreads();

    float acc[NPB][3];
#pragma unroll
    for (int nn = 0; nn < NPB; nn++) { acc[nn][0] = 0.f; acc[nn][1] = 0.f; acc[nn][2] = 0.f; }
    float redR = 0.f;                               // den (t<12) OR wsm (t in [12,14))
    int nnD = t / HEADS, hhD = t - nnD * HEADS;     // den ownership (t < 12)

    int nch = (etot + CE - 1) / CE;
    for (int ci = 0; ci < nch; ci++) {
        int i0 = ci * CE;
        int c  = min(etot - i0, CE);
        int cn = min(etot - i0 - CE, CE);   // next chunk size
        int cb = ci & 1, nb = cb ^ 1;

        // A: gather xl chunk ci -> sXL (c*24 <= 192 uint4, 3 iters); prefetch pair ci+1
        {
            int nld = c * 24;
#pragma unroll
            for (int s = 0; s < 3; s++) {
                int q = t + s * 64;
                if (q < nld) {
                    int i = q / 24, p = q - i * 24;
                    *(uint4*)&sXL[i * RS + p * 4] =
                        *(const uint4*)(xl + (size_t)sSrc[cb][i] * FEAT + p * 8);
                }
            }
        }
        int2 P;
        if (t < cn) P = pair[gbase + i0 + CE + t];
        if (t < NPB && cn > 0) {
            int lo = sStart[t] - gbase - i0 - CE;     if (lo < 0) lo = 0;
            int hi = sStart[t + 1] - gbase - i0 - CE; if (hi > cn) hi = cn;
            for (int q = lo; q < hi; q++) sDst[nb][q] = t;
        }
        __syncthreads();

        // C: alpha + exp (thread per (edge, head), t < c*6 <= 48)
        if (t < c * HEADS) {
            int i = t / HEADS, hh = t - i * HEADS;
            int nn = sDst[cb][i];
            float w = sW[cb][i];
            const uint4* pa = (const uint4*)&sXL[i * RS + hh * 16];
            const uint4* pb = (const uint4*)&sXR[nn * RS + hh * 16];
            float alpha0 = 0.f, alpha1 = 0.f;
#pragma unroll
            for (int g = 0; g < 4; g++) {
                uint4 a4 = pa[g];
                uint4 b4 = pb[g];
                float4 we0 = *(const float4*)&sWeP[hh * APAD + g * 8];
                float4 we1 = *(const float4*)&sWeP[hh * APAD + g * 8 + 4];
                float4 at0 = *(const float4*)&sAttP[hh * APAD + g * 8];
                float4 at1 = *(const float4*)&sAttP[hh * APAD + g * 8 + 4];
                float wec[8] = {we0.x, we0.y, we0.z, we0.w, we1.x, we1.y, we1.z, we1.w};
                float atc[8] = {at0.x, at0.y, at0.z, at0.w, at1.x, at1.y, at1.z, at1.w};
                unsigned aw[4] = {a4.x, a4.y, a4.z, a4.w};
                unsigned bw[4] = {b4.x, b4.y, b4.z, b4.w};
#pragma unroll
                for (int q = 0; q < 4; q++) {
                    float m0 = bu2f((unsigned short)aw[q]) + bu2f((unsigned short)bw[q]) + w * wec[q * 2];
                    m0 = fmaxf(m0, NEG_SLOPE * m0);
                    alpha0 += m0 * atc[q * 2];
                    float m1 = bu2f((unsigned short)(aw[q] >> 16)) + bu2f((unsigned short)(bw[q] >> 16)) + w * wec[q * 2 + 1];
                    m1 = fmaxf(m1, NEG_SLOPE * m1);
                    alpha1 += m1 * atc[q * 2 + 1];
                }
            }
            sEx[t] = __expf(alpha0 + alpha1);
        }
        if (t < cn) { sSrc[nb][t] = P.x; sW[nb][t] = __int_as_float(P.y); }
        __syncthreads();

        // E: accumulate — each lane owns channels {t, t+64, t+128} (heads hb, 2+hb, 4+hb)
        {
            int cwb = t >> 1;       // base word in row
            int hb  = t >> 5;       // 0/1
#pragma unroll
            for (int nn = 0; nn < NPB; nn++) {
                int lo = sStart[nn] - gbase - i0;     if (lo < 0) lo = 0;
                int hi = sStart[nn + 1] - gbase - i0; if (hi > c) hi = c;
                for (int i = lo; i < hi; i++) {
                    const unsigned int* row = &sXL[i * RS];
                    float e0 = sEx[i * HEADS + hb];
                    float e1 = sEx[i * HEADS + 2 + hb];
                    float e2 = sEx[i * HEADS + 4 + hb];
                    unsigned u0 = row[cwb], u1 = row[cwb + 32], u2 = row[cwb + 64];
                    unsigned short v0 = (t & 1) ? (unsigned short)(u0 >> 16) : (unsigned short)u0;
                    unsigned short v1 = (t & 1) ? (unsigned short)(u1 >> 16) : (unsigned short)u1;
                    unsigned short v2 = (t & 1) ? (unsigned short)(u2 >> 16) : (unsigned short)u2;
                    acc[nn][0] += e0 * bu2f(v0);
                    acc[nn][1] += e1 * bu2f(v1);
                    acc[nn][2] += e2 * bu2f(v2);
                }
            }
            if (t < NPB * HEADS) {          // den: 12 lanes
                int lo = sStart[nnD] - gbase - i0;     if (lo < 0) lo = 0;
                int hi = sStart[nnD + 1] - gbase - i0; if (hi > c) hi = c;
                for (int i = lo; i < hi; i++) redR += sEx[i * HEADS + hhD];
            } else if (t < NPB * HEADS + NPB) {   // wsm: 2 lanes
                int nw = t - NPB * HEADS;
                int lo = sStart[nw] - gbase - i0;     if (lo < 0) lo = 0;
                int hi = sStart[nw + 1] - gbase - i0; if (hi > c) hi = c;
                for (int i = lo; i < hi; i++) redR += sW[cb][i];
            }
        }
        __syncthreads();   // protects sXL/sDst overwrite next iter
    }

    if (t < NPB * HEADS) sDen[t] = redR;
    else if (t < NPB * HEADS + NPB) sWsm[t - NPB * HEADS] = redR;
    __syncthreads();

    // self-loop alpha (12 lanes, one per (nn,hh)); self xl row from GLOBAL
    if (t < NPB * HEADS) {
        int nn = nnD, hh = hhD;
        int dg = sStart[nn + 1] - sStart[nn];
        float w = sWsm[nn] / fmaxf((float)dg, 1.0f);
        const uint4* pa = (const uint4*)(xl + (size_t)(n0 + nn) * FEAT + hh * 32);
        const uint4* pb = (const uint4*)&sXR[nn * RS + hh * 16];
        float alpha0 = 0.f, alpha1 = 0.f;
#pragma unroll
        for (int g = 0; g < 4; g++) {
            uint4 a4 = pa[g];
            uint4 b4 = pb[g];
            float4 we0 = *(const float4*)&sWeP[hh * APAD + g * 8];
            float4 we1 = *(const float4*)&sWeP[hh * APAD + g * 8 + 4];
            float4 at0 = *(const float4*)&sAttP[hh * APAD + g * 8];
            float4 at1 = *(const float4*)&sAttP[hh * APAD + g * 8 + 4];
            float wec[8] = {we0.x, we0.y, we0.z, we0.w, we1.x, we1.y, we1.z, we1.w};
            float atc[8] = {at0.x, at0.y, at0.z, at0.w, at1.x, at1.y, at1.z, at1.w};
            unsigned aw[4] = {a4.x, a4.y, a4.z, a4.w};
            unsigned bw[4] = {b4.x, b4.y, b4.z, b4.w};
#pragma unroll
            for (int q = 0; q < 4; q++) {
                float m0 = bu2f((unsigned short)aw[q]) + bu2f((unsigned short)bw[q]) + w * wec[q * 2];
                m0 = fmaxf(m0, NEG_SLOPE * m0);
                alpha0 += m0 * atc[q * 2];
                float m1 = bu2f((unsigned short)(aw[q] >> 16)) + bu2f((unsigned short)(bw[q] >> 16)) + w * wec[q * 2 + 1];
                m1 = fmaxf(m1, NEG_SLOPE * m1);
                alpha1 += m1 * atc[q * 2 + 1];
            }
        }
        sExS[t] = __expf(alpha0 + alpha1);
    }
    __syncthreads();

    // epilogue: 3 channels/lane x 2 nodes; self-loop add, divide, residual+bias+relu
#pragma unroll
    for (int s = 0; s < 3; s++) {
        int ch = t + s * 64;
        float bj = bias[ch];
        int hh = ch >> 5;
#pragma unroll
        for (int nn = 0; nn < NPB; nn++) {
            float exS = sExS[nn * HEADS + hh];
            size_t off = (size_t)(n0 + nn) * FEAT + ch;
            float xsv = bu2f(xl[off]);
            float num = acc[nn][s] + exS * xsv;
            float dn  = sDen[nn * HEADS + hh] + exS;
            float val = x[off] + bj + num / dn;
            out[off] = (val > 0.f) ? val : 0.f;
        }
    }
}

extern "C" void kernel_launch(void* const* d_in, const int* in_sizes, int n_in,
                              void* d_out, int out_size, void* d_ws, size_t ws_size,
                              hipStream_t stream) {
    const float* x    = (const float*)d_in[0];
    const int*   ei   = (const int*)d_in[1];
    const float* ew   = (const float*)d_in[2];
    const float* Wl   = (const float*)d_in[3];
    const float* bl   = (const float*)d_in[4];
    const float* Wr   = (const float*)d_in[5];
    const float* br   = (const float*)d_in[6];
    const float* We   = (const float*)d_in[7];
    const float* att  = (const float*)d_in[8];
    const float* bias = (const float*)d_in[9];
    float* out = (float*)d_out;

    char* ws = (char*)d_ws;
    unsigned short* xl = (unsigned short*)(ws + XL_OFF);
    unsigned short* xr = (unsigned short*)(ws + XR_OFF);
    short* Wt     = (short*)(ws + WT_OFF);
    float* blr    = (float*)(ws + BLR_OFF);
    int2*  pair   = (int2*)(ws + PAIR_OFF);
    int*   deg    = (int*)(ws + DEG_OFF);
    int*   scan   = (int*)(ws + SCAN_OFF);
    int*   bsums  = (int*)(ws + BSUM_OFF);
    int*   boffs  = (int*)(ws + BOFF_OFF);
    int*   rank   = (int*)(ws + RANK_OFF);

    // pack Wt/blr + zero deg (replaces hipMemsetAsync launch)
    k_pack<<<(384 * FEAT + 255) / 256, 256, 0, stream>>>(Wl, Wr, bl, br, Wt, blr, deg);

    // count (atomics) and GEMM (MFMA) are independent -> one overlapped launch
    k_countgemm<<<CNT_BLOCKS + GEMM_BLOCKS, 384, 0, stream>>>(ei, deg, rank,
                                                              x, Wt, blr, xl, xr);

    k_scan1<<<NB_SCAN, 256, 0, stream>>>(deg, scan, bsums);
    k_scan2<<<1, 256, 0, stream>>>(bsums, boffs);
    k_fix<<<NB_SCAN, 256, 0, stream>>>(deg, scan, boffs);

    k_scatter<<<(N_EDGES + 255) / 256, 256, 0, stream>>>(ei, ew, deg, rank, pair);

    k_node<<<N_NODES / NPB, 64, 0, stream>>>(x, bias, att, We, scan, boffs,
                                             pair, xl, xr, out);
}